// Round 10
// baseline (375.559 us; speedup 1.0000x reference)
//
#include <hip/hip_runtime.h>
#include <hip/hip_fp16.h>
#include <cstdint>
#include <cstddef>

constexpr int R  = 512;
constexpr int C  = 16;
constexpr int HW = R * R;

constexpr int NB9   = 512;    // coarse bins: 3 bits/axis (64px cells)
constexpr int NPART = 8;      // XCD partitions for coarse counters
constexpr int NCNT  = NB9 * NPART;
constexpr int CHUNK = 4096;   // pts/block in hist/scatter

constexpr int NF    = 4096;   // fine bins: 4 bits/axis (32px cells)
constexpr int KMAX  = 16;     // refine: max recs per thread (cap 8192/coarse bin)

// tile geometry: 33x33 texels, 16B/texel (8 fp16 channels), per plane
constexpr int TW   = 33;
constexpr int TROW = TW * 16;      // 528 B row stride (132 dwords = 4 mod 32 banks)
constexpr int TPL  = TW * TROW;    // 17424 B per plane tile
// 3*TPL = 52272 B LDS -> 3 blocks/CU (156.8KB of 160KB)

typedef float v4f __attribute__((ext_vector_type(4)));
typedef int   v4i __attribute__((ext_vector_type(4)));

// ---- unified, bit-exact coordinate helpers (used by ALL kernels) ----------
__device__ __forceinline__ float tcoord(float g) {
    return __fmul_rn(__fadd_rn(g, 1.0f), 255.5f);   // == ((g+1)*0.5)*511 bit-exact
}
__device__ __forceinline__ int cell512(float g) {
    const int i = (int)tcoord(g);
    return min(max(i, 0), R - 1);
}
__device__ __forceinline__ uint32_t mortonN(int a, int b, int c, int nb) {
    uint32_t k = 0;
#pragma unroll
    for (int i = 0; i < 5; ++i) {
        if (i < nb) {
            k |= ((uint32_t)((a >> i) & 1)) << (3 * i + 2);
            k |= ((uint32_t)((b >> i) & 1)) << (3 * i + 1);
            k |= ((uint32_t)((c >> i) & 1)) << (3 * i + 0);
        }
    }
    return k;
}
__device__ __forceinline__ uint32_t key9(float a, float b, float c) {
    return mortonN(cell512(a) >> 6, cell512(b) >> 6, cell512(c) >> 6, 3);
}

// ---------------------------------------------------------------------------
// Transpose (C,H,W) fp32 -> two channel-split (H,W,8ch) fp16 arrays:
// half h at t + h*(3*HW*8). 16B texels -> staging loads are dense.
// grid = (R, R/64, 3), block = 256
// ---------------------------------------------------------------------------
__global__ __launch_bounds__(256) void transpose_chw_hwc_hs(
    const float* __restrict__ p0, const float* __restrict__ p1,
    const float* __restrict__ p2, __half* __restrict__ dst)
{
    __shared__ float lds[64 * 17];
    const int y  = blockIdx.x;
    const int x0 = blockIdx.y * 64;
    const int pl = blockIdx.z;
    const float* src = (pl == 0) ? p0 : ((pl == 1) ? p1 : p2);
    const int tid = threadIdx.x;
    const int xl  = tid & 63;
    const int c0  = tid >> 6;
#pragma unroll
    for (int i = 0; i < 4; ++i) {
        const int c = c0 * 4 + i;
        lds[xl * 17 + c] = src[c * HW + y * R + x0 + xl];
    }
    __syncthreads();
    if (tid < 128) {
        const int x = tid & 63;
        const int h = tid >> 6;              // channel half
        uint4 v;
        unsigned int* vp = (unsigned int*)&v;
#pragma unroll
        for (int i = 0; i < 4; ++i) {
            const float a = lds[x * 17 + 8 * h + 2 * i + 0];
            const float b = lds[x * 17 + 8 * h + 2 * i + 1];
            const __half2 hh = __floats2half2_rn(a, b);
            vp[i] = *(const unsigned int*)&hh;
        }
        __half* th = dst + (size_t)h * (3 * (size_t)HW * 8);
        *(uint4*)(th + ((size_t)pl * HW + (size_t)y * R + x0 + x) * 8) = v;
    }
}

// ---------------------------------------------------------------------------
// Coarse histogram (9-bit) with LDS aggregation.
// ---------------------------------------------------------------------------
__global__ __launch_bounds__(256) void hist_pts(
    const float* __restrict__ x, unsigned int* __restrict__ counts, int B)
{
    __shared__ unsigned int h[NB9];
    const int tid = threadIdx.x;
    for (int i = tid; i < NB9; i += 256) h[i] = 0;
    __syncthreads();
    const int start = blockIdx.x * CHUNK;
#pragma unroll
    for (int j = 0; j < CHUNK / 256; ++j) {
        const int i = start + j * 256 + tid;
        if (i < B) {
            const float a = x[(size_t)i * 3 + 0];
            const float b = x[(size_t)i * 3 + 1];
            const float c = x[(size_t)i * 3 + 2];
            atomicAdd(&h[key9(a, b, c)], 1u);
        }
    }
    __syncthreads();
    unsigned int* cb = counts + (blockIdx.x & (NPART - 1)) * NB9;
    for (int i = tid; i < NB9; i += 256) {
        const unsigned int c = h[i];
        if (c) atomicAdd(&cb[i], c);
    }
}

// Scan 4096 coarse counters in LOGICAL (key,part) order; counters part-major.
// Emits binStart[key] coarse starts.
__global__ __launch_bounds__(1024) void scan_counts(
    const unsigned int* __restrict__ counts, unsigned int* __restrict__ cursor,
    unsigned int* __restrict__ binStart)
{
    __shared__ unsigned int s[1024];
    const int t = threadIdx.x;
    unsigned int v[4];
    unsigned int sum = 0;
#pragma unroll
    for (int i = 0; i < 4; ++i) {
        const int L = t * 4 + i;            // logical = key*NPART + part
        const int key = L >> 3, part = L & 7;
        v[i] = counts[part * NB9 + key];
        sum += v[i];
    }
    unsigned int run = 0;
#pragma unroll
    for (int i = 0; i < 4; ++i) { const unsigned int tmp = v[i]; v[i] = run; run += tmp; }
    s[t] = sum;
    __syncthreads();
    unsigned int incl = sum;
    for (int off = 1; off < 1024; off <<= 1) {
        const unsigned int u = (t >= off) ? s[t - off] : 0u;
        __syncthreads();
        incl += u;
        s[t] = incl;
        __syncthreads();
    }
    const unsigned int excl = incl - sum;
#pragma unroll
    for (int i = 0; i < 4; ++i) {
        const int L = t * 4 + i;
        const int key = L >> 3, part = L & 7;
        cursor[part * NB9 + key] = excl + v[i];
        if (part == 0) binStart[key] = excl + v[i];
    }
    if (t == 1023) binStart[NB9] = incl;    // = B
}

// ---------------------------------------------------------------------------
// Coarse scatter: block-local counting sort (bin-sorted, run-coalesced writes).
// ---------------------------------------------------------------------------
__global__ __launch_bounds__(256) void scatter_pts(
    const float* __restrict__ x, unsigned int* __restrict__ cursor,
    int4* __restrict__ recs, int B)
{
    __shared__ unsigned int h[NB9];
    __shared__ unsigned int gbase[NB9];
    __shared__ unsigned int lpre[NB9];
    __shared__ unsigned int lcur[NB9];
    __shared__ int4 buf[CHUNK];
    __shared__ unsigned short binOf[CHUNK];

    const int tid   = threadIdx.x;
    const int start = blockIdx.x * CHUNK;
    const int V     = min(CHUNK, B - start);

    for (int i = tid; i < NB9; i += 256) h[i] = 0;
    __syncthreads();

    float pa[CHUNK / 256], pb_[CHUNK / 256], pc[CHUNK / 256];
    unsigned int pk[CHUNK / 256];
#pragma unroll
    for (int j = 0; j < CHUNK / 256; ++j) {
        const int i = start + j * 256 + tid;
        pk[j] = 0xFFFFFFFFu;
        if (i < B) {
            pa[j] = x[(size_t)i * 3 + 0];
            pb_[j] = x[(size_t)i * 3 + 1];
            pc[j] = x[(size_t)i * 3 + 2];
            pk[j] = key9(pa[j], pb_[j], pc[j]);
            atomicAdd(&h[pk[j]], 1u);
        }
    }
    __syncthreads();

    unsigned int* cb = cursor + (blockIdx.x & (NPART - 1)) * NB9;
    for (int b = tid; b < NB9; b += 256) {
        const unsigned int c = h[b];
        gbase[b] = c ? atomicAdd(&cb[b], c) : 0u;
    }
    if (tid < 64) {
        unsigned int loc[8];
        unsigned int tot = 0;
#pragma unroll
        for (int j = 0; j < 8; ++j) { loc[j] = h[tid * 8 + j]; tot += loc[j]; }
        unsigned int run = tot;
#pragma unroll
        for (int d = 1; d < 64; d <<= 1) {
            const unsigned int u = __shfl_up(run, (unsigned)d, 64);
            if (tid >= d) run += u;
        }
        unsigned int excl = run - tot;
#pragma unroll
        for (int j = 0; j < 8; ++j) { lpre[tid * 8 + j] = excl; excl += loc[j]; }
    }
    __syncthreads();
    for (int b = tid; b < NB9; b += 256) lcur[b] = lpre[b];
    __syncthreads();

#pragma unroll
    for (int j = 0; j < CHUNK / 256; ++j) {
        if (pk[j] != 0xFFFFFFFFu) {
            const int i = start + j * 256 + tid;
            const unsigned int rk = atomicAdd(&lcur[pk[j]], 1u);
            buf[rk] = make_int4(__float_as_int(pa[j]), __float_as_int(pb_[j]),
                                __float_as_int(pc[j]), i);
            binOf[rk] = (unsigned short)pk[j];
        }
    }
    __syncthreads();

    for (int idx = tid; idx < V; idx += 256) {
        const int4 rc = buf[idx];
        const int  k  = binOf[idx];
        const unsigned int dest = gbase[k] + ((unsigned int)idx - lpre[k]);
        const v4i rv = { rc.x, rc.y, rc.z, rc.w };
        __builtin_nontemporal_store(rv, (v4i*)&recs[dest]);
    }
}

// ---------------------------------------------------------------------------
// Refine: in-place sort of each coarse bin by the 3 next Morton bits
// (-> 12-bit order), records held in registers across the barrier.
// Emits fineStart[4096].
// ---------------------------------------------------------------------------
__global__ __launch_bounds__(512) void refine_pts(
    const unsigned int* __restrict__ binStart,
    int4* __restrict__ recs,
    unsigned int* __restrict__ fineStart)
{
    __shared__ unsigned int h8[8];
    __shared__ unsigned int pre[8];
    const int k = blockIdx.x;
    const unsigned int s0 = binStart[k];
    const unsigned int s1 = binStart[k + 1];
    const int tid = threadIdx.x;
    if (tid < 8) h8[tid] = 0;
    __syncthreads();

    int4 rc[KMAX];
    unsigned int rs[KMAX];                  // (rank<<3)|sub
#pragma unroll
    for (int j = 0; j < KMAX; ++j) {
        const unsigned int idx = s0 + (unsigned)tid + (unsigned)j * 512u;
        rs[j] = 0xFFFFFFFFu;
        if (idx < s1) {
            rc[j] = recs[idx];
            const int sub = (((cell512(__int_as_float(rc[j].x)) >> 5) & 1) << 2)
                          | (((cell512(__int_as_float(rc[j].y)) >> 5) & 1) << 1)
                          | (((cell512(__int_as_float(rc[j].z)) >> 5) & 1) << 0);
            const unsigned int rank = atomicAdd(&h8[sub], 1u);
            rs[j] = (rank << 3) | (unsigned)sub;
        }
    }
    __syncthreads();

    if (tid == 0) {
        unsigned int run = 0;
#pragma unroll
        for (int s = 0; s < 8; ++s) {
            pre[s] = run;
            fineStart[k * 8 + s] = s0 + run;
            run += h8[s];
        }
    }
    __syncthreads();

#pragma unroll
    for (int j = 0; j < KMAX; ++j) {
        if (rs[j] != 0xFFFFFFFFu) {
            const unsigned int sub  = rs[j] & 7u;
            const unsigned int rank = rs[j] >> 3;
            recs[s0 + pre[sub] + rank] = rc[j];
        }
    }
}

// ---------------------------------------------------------------------------
// Tile sampler: 8192 blocks = 4096 fine bins x 2 channel halves. Each block
// stages 3 plane tiles (33x33 texels, 16B/texel from the channel-split array)
// into LDS (51KB, 3 blocks/CU -> 24 waves/CU), then samples ~488 points from
// LDS (12 ds_read_b128/point-lane). XCD-chunked bin mapping; both halves of a
// bin land on the same XCD so out-lines stay in one L2.
// ---------------------------------------------------------------------------
__global__ __launch_bounds__(512) void sample_tile(
    const int4* __restrict__ recs, const __half* __restrict__ t,
    const unsigned int* __restrict__ fineStart,
    float* __restrict__ out, int B)
{
    __shared__ __align__(16) unsigned char tile[3 * TPL];

    const unsigned int bid = blockIdx.x;
    const unsigned int g   = (bid & 7u) * 1024u + (bid >> 3);  // XCD-chunked
    const unsigned int f   = g >> 1;
    const int          h   = (int)(g & 1u);
    const unsigned int s0  = fineStart[f];
    const unsigned int s1  = (f == NF - 1) ? (unsigned int)B : fineStart[f + 1];
    if (s0 >= s1) return;

    // decode 12-bit fine Morton -> 4-bit cell coords
    int c0 = 0, c1 = 0, c2 = 0;
#pragma unroll
    for (int i = 0; i < 4; ++i) {
        c0 |= (int)((f >> (3 * i + 2)) & 1u) << i;
        c1 |= (int)((f >> (3 * i + 1)) & 1u) << i;
        c2 |= (int)((f >> (3 * i + 0)) & 1u) << i;
    }
    const int gx0[3] = { c0 * 32, c0 * 32, c1 * 32 };  // width cell base per plane
    const int gy0[3] = { c1 * 32, c2 * 32, c2 * 32 };  // height cell base per plane

    const int tid = threadIdx.x;
    const __half* th = t + (size_t)h * (3 * (size_t)HW * 8);

    // ---- stage: 3 x 33 x 33 dense 16B chunks ----
    for (int idx = tid; idx < 3 * TW * TW; idx += 512) {
        const int pl  = idx / (TW * TW);
        const int rem = idx - pl * (TW * TW);
        const int row = rem / TW;
        const int col = rem - row * TW;
        const int gy = min(gy0[pl] + row, R - 1);
        const int gx = min(gx0[pl] + col, R - 1);
        const uint4 v = *(const uint4*)(th + ((size_t)pl * HW + (size_t)gy * R + gx) * 8);
        *(uint4*)(tile + pl * TPL + row * TROW + col * 16) = v;
    }
    __syncthreads();

    // ---- sample: one point per lane per iteration, 8 channels ----
    for (unsigned int i = s0 + (unsigned int)tid; i < s1; i += 512u) {
        const v4i rv = __builtin_nontemporal_load((const v4i*)&recs[i]);
        const float xv0 = __int_as_float(rv.x);
        const float xv1 = __int_as_float(rv.y);
        const float xv2 = __int_as_float(rv.z);
        const int orig  = rv.w;

        float acc[8] = {1.f, 1.f, 1.f, 1.f, 1.f, 1.f, 1.f, 1.f};

#pragma unroll
        for (int pl = 0; pl < 3; ++pl) {
            const float gx = (pl == 2) ? xv1 : xv0;
            const float gy = (pl == 0) ? xv1 : xv2;
            const float px = tcoord(gx);
            const float py = tcoord(gy);
            const float fx = floorf(px), fy = floorf(py);
            const float wx = px - fx,    wy = py - fy;
            const int x0 = min(max((int)fx, 0), R - 1);
            const int y0 = min(max((int)fy, 0), R - 1);
            const int x1 = min(x0 + 1, R - 1);
            const int y1 = min(y0 + 1, R - 1);
            const int lx0 = x0 & 31, lx1 = lx0 + (x1 - x0);
            const int ly0 = y0 & 31, ly1 = ly0 + (y1 - y0);

            const unsigned char* tb = tile + pl * TPL;
            const uint4 v00 = *(const uint4*)(tb + ly0 * TROW + lx0 * 16);
            const uint4 v01 = *(const uint4*)(tb + ly0 * TROW + lx1 * 16);
            const uint4 v10 = *(const uint4*)(tb + ly1 * TROW + lx0 * 16);
            const uint4 v11 = *(const uint4*)(tb + ly1 * TROW + lx1 * 16);

            const float w00 = (1.f - wx) * (1.f - wy);
            const float w01 = wx * (1.f - wy);
            const float w10 = (1.f - wx) * wy;
            const float w11 = wx * wy;

            const __half2* a0 = (const __half2*)&v00;
            const __half2* a1 = (const __half2*)&v01;
            const __half2* a2 = (const __half2*)&v10;
            const __half2* a3 = (const __half2*)&v11;
#pragma unroll
            for (int i2 = 0; i2 < 4; ++i2) {
                const float2 f00 = __half22float2(a0[i2]);
                const float2 f01 = __half22float2(a1[i2]);
                const float2 f10 = __half22float2(a2[i2]);
                const float2 f11 = __half22float2(a3[i2]);
                acc[2 * i2 + 0] *= f00.x * w00 + f01.x * w01 + f10.x * w10 + f11.x * w11;
                acc[2 * i2 + 1] *= f00.y * w00 + f01.y * w01 + f10.y * w10 + f11.y * w11;
            }
        }

        float* o = out + (size_t)orig * C + h * 8;
        const v4f o0 = { acc[0], acc[1], acc[2], acc[3] };
        const v4f o1 = { acc[4], acc[5], acc[6], acc[7] };
        __builtin_nontemporal_store(o0, (v4f*)(o + 0));
        __builtin_nontemporal_store(o1, (v4f*)(o + 4));
    }
}

// ============================ fallback paths ================================
__global__ __launch_bounds__(256) void transpose_chw_hwc(
    const float* __restrict__ p0, const float* __restrict__ p1,
    const float* __restrict__ p2, float* __restrict__ dst)
{
    __shared__ float lds[64 * 17];
    const int y  = blockIdx.x;
    const int x0 = blockIdx.y * 64;
    const int pl = blockIdx.z;
    const float* src = (pl == 0) ? p0 : ((pl == 1) ? p1 : p2);
    const int tid = threadIdx.x;
    const int xl  = tid & 63;
    const int c0  = tid >> 6;
#pragma unroll
    for (int i = 0; i < 4; ++i) {
        const int c = c0 * 4 + i;
        lds[xl * 17 + c] = src[c * HW + y * R + x0 + xl];
    }
    __syncthreads();
    float* dbase = dst + ((size_t)pl * HW + (size_t)(y * R + x0)) * C;
#pragma unroll
    for (int i = 0; i < 4; ++i) {
        const int j = tid + i * 256;
        dbase[j] = lds[(j >> 4) * 17 + (j & 15)];
    }
}

__global__ __launch_bounds__(256) void sample_hwc(
    const float* __restrict__ x, const float* __restrict__ t,
    float* __restrict__ out, int B)
{
    const int tid = blockIdx.x * 256 + threadIdx.x;
    const int p   = tid >> 2;
    const int cg  = tid & 3;
    if (p >= B) return;

    const float xv0 = x[(size_t)p * 3 + 0];
    const float xv1 = x[(size_t)p * 3 + 1];
    const float xv2 = x[(size_t)p * 3 + 2];
    const float gxs[3] = { xv0, xv0, xv1 };
    const float gys[3] = { xv1, xv2, xv2 };
    float4 acc = make_float4(1.f, 1.f, 1.f, 1.f);

#pragma unroll
    for (int pl = 0; pl < 3; ++pl) {
        const float gx = gxs[pl], gy = gys[pl];
        const float px = (gx + 1.0f) * 0.5f * (float)(R - 1);
        const float py = (gy + 1.0f) * 0.5f * (float)(R - 1);
        const float x0f = floorf(px), y0f = floorf(py);
        const float wx = px - x0f,   wy = py - y0f;
        int x0 = (int)x0f; x0 = min(max(x0, 0), R - 1);
        int y0 = (int)y0f; y0 = min(max(y0, 0), R - 1);
        const int x1 = min(x0 + 1, R - 1);
        const int y1 = min(y0 + 1, R - 1);

        const float* pb = t + (size_t)pl * (size_t)(HW * C) + cg * 4;
        const float4 p00 = *(const float4*)(pb + (size_t)(y0 * R + x0) * C);
        const float4 p01 = *(const float4*)(pb + (size_t)(y0 * R + x1) * C);
        const float4 p10 = *(const float4*)(pb + (size_t)(y1 * R + x0) * C);
        const float4 p11 = *(const float4*)(pb + (size_t)(y1 * R + x1) * C);

        const float w00 = (1.f - wx) * (1.f - wy);
        const float w01 = wx * (1.f - wy);
        const float w10 = (1.f - wx) * wy;
        const float w11 = wx * wy;

        float4 fv;
        fv.x = p00.x * w00 + p01.x * w01 + p10.x * w10 + p11.x * w11;
        fv.y = p00.y * w00 + p01.y * w01 + p10.y * w10 + p11.y * w11;
        fv.z = p00.z * w00 + p01.z * w01 + p10.z * w10 + p11.z * w11;
        fv.w = p00.w * w00 + p01.w * w01 + p10.w * w10 + p11.w * w11;

        acc.x *= fv.x; acc.y *= fv.y; acc.z *= fv.z; acc.w *= fv.w;
    }

    *(float4*)(out + (size_t)p * C + cg * 4) = acc;
}

__global__ __launch_bounds__(256) void sample_chw(
    const float* __restrict__ x,
    const float* __restrict__ p0, const float* __restrict__ p1,
    const float* __restrict__ p2, float* __restrict__ out, int B)
{
    const int tid = blockIdx.x * 256 + threadIdx.x;
    const int p   = tid >> 2;
    const int cg  = tid & 3;
    if (p >= B) return;
    const float xv0 = x[(size_t)p * 3 + 0];
    const float xv1 = x[(size_t)p * 3 + 1];
    const float xv2 = x[(size_t)p * 3 + 2];
    const float gxs[3] = { xv0, xv0, xv1 };
    const float gys[3] = { xv1, xv2, xv2 };
    const float* planes[3] = { p0, p1, p2 };
    float acc[4] = {1.f, 1.f, 1.f, 1.f};
#pragma unroll
    for (int pl = 0; pl < 3; ++pl) {
        const float gx = gxs[pl], gy = gys[pl];
        const float px = (gx + 1.0f) * 0.5f * (float)(R - 1);
        const float py = (gy + 1.0f) * 0.5f * (float)(R - 1);
        const float x0f = floorf(px), y0f = floorf(py);
        const float wx = px - x0f,   wy = py - y0f;
        int x0 = (int)x0f; x0 = min(max(x0, 0), R - 1);
        int y0 = (int)y0f; y0 = min(max(y0, 0), R - 1);
        const int x1 = min(x0 + 1, R - 1);
        const int y1 = min(y0 + 1, R - 1);
        const float w00 = (1.f - wx) * (1.f - wy);
        const float w01 = wx * (1.f - wy);
        const float w10 = (1.f - wx) * wy;
        const float w11 = wx * wy;
        const float* pb = planes[pl];
#pragma unroll
        for (int k = 0; k < 4; ++k) {
            const int c = cg * 4 + k;
            const float* b2 = pb + (size_t)c * HW;
            const float v00 = b2[y0 * R + x0];
            const float v01 = b2[y0 * R + x1];
            const float v10 = b2[y1 * R + x0];
            const float v11 = b2[y1 * R + x1];
            acc[k] *= v00 * w00 + v01 * w01 + v10 * w10 + v11 * w11;
        }
    }
    float* o = out + (size_t)p * C + cg * 4;
    o[0] = acc[0]; o[1] = acc[1]; o[2] = acc[2]; o[3] = acc[3];
}

// ===========================================================================
extern "C" void kernel_launch(void* const* d_in, const int* in_sizes, int n_in,
                              void* d_out, int out_size, void* d_ws, size_t ws_size,
                              hipStream_t stream) {
    const float* x  = (const float*)d_in[0];
    const float* p0 = (const float*)d_in[1];
    const float* p1 = (const float*)d_in[2];
    const float* p2 = (const float*)d_in[3];
    float* out = (float*)d_out;
    const int B = in_sizes[0] / 3;

    const size_t t_bytes    = (size_t)3 * HW * C * sizeof(__half);     // 24 MiB (2 halves)
    const size_t recs_bytes = (size_t)B * 16;                          // 32 MB
    const size_t cnt_bytes  = (size_t)NCNT * 4;                        // 16 KiB
    const size_t bs_bytes   = (size_t)(NB9 + 1) * 4;
    const size_t fs_bytes   = (size_t)NF * 4;

    const size_t off_t      = 0;
    const size_t off_recs   = (t_bytes + 255) & ~(size_t)255;
    const size_t off_counts = (off_recs + recs_bytes + 255) & ~(size_t)255;
    const size_t off_cursor = (off_counts + cnt_bytes + 255) & ~(size_t)255;
    const size_t off_bs     = (off_cursor + cnt_bytes + 255) & ~(size_t)255;
    const size_t off_fs     = (off_bs + bs_bytes + 255) & ~(size_t)255;
    const size_t need_full  = off_fs + fs_bytes;

    const size_t need_fp32  = (size_t)3 * HW * C * sizeof(float);      // 48 MiB

    if (d_ws != nullptr && ws_size >= need_full) {
        __half*       t      = (__half*)((char*)d_ws + off_t);
        int4*         recs   = (int4*)((char*)d_ws + off_recs);
        unsigned int* counts = (unsigned int*)((char*)d_ws + off_counts);
        unsigned int* cursor = (unsigned int*)((char*)d_ws + off_cursor);
        unsigned int* bstart = (unsigned int*)((char*)d_ws + off_bs);
        unsigned int* fstart = (unsigned int*)((char*)d_ws + off_fs);

        dim3 tg(R, R / 64, 3);
        transpose_chw_hwc_hs<<<tg, 256, 0, stream>>>(p0, p1, p2, t);

        hipMemsetAsync(counts, 0, cnt_bytes, stream);
        const int nblkP = (B + CHUNK - 1) / CHUNK;
        hist_pts<<<nblkP, 256, 0, stream>>>(x, counts, B);
        scan_counts<<<1, 1024, 0, stream>>>(counts, cursor, bstart);
        scatter_pts<<<nblkP, 256, 0, stream>>>(x, cursor, recs, B);
        refine_pts<<<NB9, 512, 0, stream>>>(bstart, recs, fstart);
        sample_tile<<<NF * 2, 512, 0, stream>>>(recs, t, fstart, out, B);
    } else if (d_ws != nullptr && ws_size >= need_fp32) {
        float* tf = (float*)d_ws;
        dim3 tg(R, R / 64, 3);
        transpose_chw_hwc<<<tg, 256, 0, stream>>>(p0, p1, p2, tf);
        const int nthr = B * 4;
        const int nblk = (nthr + 255) / 256;
        sample_hwc<<<nblk, 256, 0, stream>>>(x, tf, out, B);
    } else {
        const int nthr = B * 4;
        const int nblk = (nthr + 255) / 256;
        sample_chw<<<nblk, 256, 0, stream>>>(x, p0, p1, p2, out, B);
    }
}

// Round 11
// 166.110 us; speedup vs baseline: 2.2609x; 2.2609x over previous
//
#include <hip/hip_runtime.h>
#include <hip/hip_fp16.h>
#include <cstdint>
#include <cstddef>

constexpr int R  = 512;
constexpr int C  = 16;
constexpr int HW = R * R;

constexpr int NB9   = 512;    // coarse bins: 3 bits/axis (64px cells)
constexpr int NPART = 8;      // XCD partitions for coarse counters
constexpr int NCNT  = NB9 * NPART;
constexpr int CHUNK = 4096;   // pts/block in hist/scatter
constexpr int KMAX  = 16;     // refine: recs per thread (cap 8192 per coarse bin)

typedef float v4f __attribute__((ext_vector_type(4)));
typedef int   v4i __attribute__((ext_vector_type(4)));

// ---- unified, bit-exact coordinate helpers ----------
__device__ __forceinline__ float tcoord(float g) {
    return __fmul_rn(__fadd_rn(g, 1.0f), 255.5f);   // bit-exact == ((g+1)*0.5f)*511
}
__device__ __forceinline__ int cell512(float g) {
    const int i = (int)tcoord(g);
    return min(max(i, 0), R - 1);
}
__device__ __forceinline__ uint32_t mortonN(int a, int b, int c, int nb) {
    uint32_t k = 0;
#pragma unroll
    for (int i = 0; i < 5; ++i) {
        if (i < nb) {
            k |= ((uint32_t)((a >> i) & 1)) << (3 * i + 2);
            k |= ((uint32_t)((b >> i) & 1)) << (3 * i + 1);
            k |= ((uint32_t)((c >> i) & 1)) << (3 * i + 0);
        }
    }
    return k;
}
__device__ __forceinline__ uint32_t key9(float a, float b, float c) {
    return mortonN(cell512(a) >> 6, cell512(b) >> 6, cell512(c) >> 6, 3);
}

// ---------------------------------------------------------------------------
// Transpose (C,H,W) fp32 -> (H,W,C) fp16 (interleaved 32B texels).
// ---------------------------------------------------------------------------
__global__ __launch_bounds__(256) void transpose_chw_hwc_h(
    const float* __restrict__ p0, const float* __restrict__ p1,
    const float* __restrict__ p2, __half* __restrict__ dst)
{
    __shared__ float lds[64 * 17];
    const int y  = blockIdx.x;
    const int x0 = blockIdx.y * 64;
    const int pl = blockIdx.z;
    const float* src = (pl == 0) ? p0 : ((pl == 1) ? p1 : p2);
    const int tid = threadIdx.x;
    const int xl  = tid & 63;
    const int c0  = tid >> 6;
#pragma unroll
    for (int i = 0; i < 4; ++i) {
        const int c = c0 * 4 + i;
        lds[xl * 17 + c] = src[c * HW + y * R + x0 + xl];
    }
    __syncthreads();
    __half2* dbase = (__half2*)(dst + ((size_t)pl * HW + (size_t)(y * R + x0)) * C);
#pragma unroll
    for (int i = 0; i < 2; ++i) {
        const int j  = tid + i * 256;
        const int e0 = 2 * j;
        const float a = lds[(e0 >> 4) * 17 + (e0 & 15)];
        const float b = lds[(e0 >> 4) * 17 + ((e0 & 15) + 1)];
        dbase[j] = __floats2half2_rn(a, b);
    }
}

// ---------------------------------------------------------------------------
// Coarse histogram (9-bit) with LDS aggregation.
// ---------------------------------------------------------------------------
__global__ __launch_bounds__(256) void hist_pts(
    const float* __restrict__ x, unsigned int* __restrict__ counts, int B)
{
    __shared__ unsigned int h[NB9];
    const int tid = threadIdx.x;
    for (int i = tid; i < NB9; i += 256) h[i] = 0;
    __syncthreads();
    const int start = blockIdx.x * CHUNK;
#pragma unroll
    for (int j = 0; j < CHUNK / 256; ++j) {
        const int i = start + j * 256 + tid;
        if (i < B) {
            const float a = x[(size_t)i * 3 + 0];
            const float b = x[(size_t)i * 3 + 1];
            const float c = x[(size_t)i * 3 + 2];
            atomicAdd(&h[key9(a, b, c)], 1u);
        }
    }
    __syncthreads();
    unsigned int* cb = counts + (blockIdx.x & (NPART - 1)) * NB9;
    for (int i = tid; i < NB9; i += 256) {
        const unsigned int c = h[i];
        if (c) atomicAdd(&cb[i], c);
    }
}

// Scan 4096 coarse counters in LOGICAL (key,part) order (records bin-major);
// counters part-major in memory. Emits binStart[key] for refine.
__global__ __launch_bounds__(1024) void scan_counts(
    const unsigned int* __restrict__ counts, unsigned int* __restrict__ cursor,
    unsigned int* __restrict__ binStart)
{
    __shared__ unsigned int s[1024];
    const int t = threadIdx.x;
    unsigned int v[4];
    unsigned int sum = 0;
#pragma unroll
    for (int i = 0; i < 4; ++i) {
        const int L = t * 4 + i;            // logical = key*NPART + part
        const int key = L >> 3, part = L & 7;
        v[i] = counts[part * NB9 + key];
        sum += v[i];
    }
    unsigned int run = 0;
#pragma unroll
    for (int i = 0; i < 4; ++i) { const unsigned int tmp = v[i]; v[i] = run; run += tmp; }
    s[t] = sum;
    __syncthreads();
    unsigned int incl = sum;
    for (int off = 1; off < 1024; off <<= 1) {
        const unsigned int u = (t >= off) ? s[t - off] : 0u;
        __syncthreads();
        incl += u;
        s[t] = incl;
        __syncthreads();
    }
    const unsigned int excl = incl - sum;
#pragma unroll
    for (int i = 0; i < 4; ++i) {
        const int L = t * 4 + i;
        const int key = L >> 3, part = L & 7;
        cursor[part * NB9 + key] = excl + v[i];
        if (part == 0) binStart[key] = excl + v[i];
    }
    if (t == 1023) binStart[NB9] = incl;    // = B
}

// ---------------------------------------------------------------------------
// Coarse scatter: block-local counting sort (bin-sorted, run-coalesced writes).
// ---------------------------------------------------------------------------
__global__ __launch_bounds__(256) void scatter_pts(
    const float* __restrict__ x, unsigned int* __restrict__ cursor,
    int4* __restrict__ recs, int B)
{
    __shared__ unsigned int h[NB9];
    __shared__ unsigned int gbase[NB9];
    __shared__ unsigned int lpre[NB9];
    __shared__ unsigned int lcur[NB9];
    __shared__ int4 buf[CHUNK];
    __shared__ unsigned short binOf[CHUNK];

    const int tid   = threadIdx.x;
    const int start = blockIdx.x * CHUNK;
    const int V     = min(CHUNK, B - start);

    for (int i = tid; i < NB9; i += 256) h[i] = 0;
    __syncthreads();

    float pa[CHUNK / 256], pb_[CHUNK / 256], pc[CHUNK / 256];
    unsigned int pk[CHUNK / 256];
#pragma unroll
    for (int j = 0; j < CHUNK / 256; ++j) {
        const int i = start + j * 256 + tid;
        pk[j] = 0xFFFFFFFFu;
        if (i < B) {
            pa[j] = x[(size_t)i * 3 + 0];
            pb_[j] = x[(size_t)i * 3 + 1];
            pc[j] = x[(size_t)i * 3 + 2];
            pk[j] = key9(pa[j], pb_[j], pc[j]);
            atomicAdd(&h[pk[j]], 1u);
        }
    }
    __syncthreads();

    unsigned int* cb = cursor + (blockIdx.x & (NPART - 1)) * NB9;
    for (int b = tid; b < NB9; b += 256) {
        const unsigned int c = h[b];
        gbase[b] = c ? atomicAdd(&cb[b], c) : 0u;
    }
    if (tid < 64) {
        unsigned int loc[8];
        unsigned int tot = 0;
#pragma unroll
        for (int j = 0; j < 8; ++j) { loc[j] = h[tid * 8 + j]; tot += loc[j]; }
        unsigned int run = tot;
#pragma unroll
        for (int d = 1; d < 64; d <<= 1) {
            const unsigned int u = __shfl_up(run, (unsigned)d, 64);
            if (tid >= d) run += u;
        }
        unsigned int excl = run - tot;
#pragma unroll
        for (int j = 0; j < 8; ++j) { lpre[tid * 8 + j] = excl; excl += loc[j]; }
    }
    __syncthreads();
    for (int b = tid; b < NB9; b += 256) lcur[b] = lpre[b];
    __syncthreads();

#pragma unroll
    for (int j = 0; j < CHUNK / 256; ++j) {
        if (pk[j] != 0xFFFFFFFFu) {
            const int i = start + j * 256 + tid;
            const unsigned int rk = atomicAdd(&lcur[pk[j]], 1u);
            buf[rk] = make_int4(__float_as_int(pa[j]), __float_as_int(pb_[j]),
                                __float_as_int(pc[j]), i);
            binOf[rk] = (unsigned short)pk[j];
        }
    }
    __syncthreads();

    for (int idx = tid; idx < V; idx += 256) {
        const int4 rc = buf[idx];
        const int  k  = binOf[idx];
        const unsigned int dest = gbase[k] + ((unsigned int)idx - lpre[k]);
        const v4i rv = { rc.x, rc.y, rc.z, rc.w };
        __builtin_nontemporal_store(rv, (v4i*)&recs[dest]);
    }
}

// ---------------------------------------------------------------------------
// Refine: in-place permutation of each coarse bin's records by the 6 finer
// Morton bits -> overall 15-bit order (16px cells, 3-plane gather window
// ~28KB ~= L1). Records held in registers across the barrier; one block per
// coarse bin; no index table needed (sampler streams recs linearly).
// ---------------------------------------------------------------------------
__global__ __launch_bounds__(512) void refine_pts(
    const unsigned int* __restrict__ binStart, int4* __restrict__ recs)
{
    __shared__ unsigned int h[64];
    __shared__ unsigned int pre[64];
    const int k = blockIdx.x;
    const unsigned int s0 = binStart[k];
    const unsigned int s1 = binStart[k + 1];
    const int tid = threadIdx.x;
    if (tid < 64) h[tid] = 0;
    __syncthreads();

    int4 rc[KMAX];
    unsigned int rs[KMAX];                  // (rank<<6)|sub
#pragma unroll
    for (int j = 0; j < KMAX; ++j) {
        const unsigned int idx = s0 + (unsigned)tid + (unsigned)j * 512u;
        rs[j] = 0xFFFFFFFFu;
        if (idx < s1) {
            rc[j] = recs[idx];
            const int c0 = cell512(__int_as_float(rc[j].x)) >> 4;
            const int c1 = cell512(__int_as_float(rc[j].y)) >> 4;
            const int c2 = cell512(__int_as_float(rc[j].z)) >> 4;
            const unsigned int sub = mortonN(c0, c1, c2, 5) & 63u;
            const unsigned int rank = atomicAdd(&h[sub], 1u);
            rs[j] = (rank << 6) | sub;
        }
    }
    __syncthreads();

    if (tid < 64) {
        const unsigned int v = h[tid];
        unsigned int run = v;
#pragma unroll
        for (int d = 1; d < 64; d <<= 1) {
            const unsigned int u = __shfl_up(run, (unsigned)d, 64);
            if (tid >= d) run += u;
        }
        pre[tid] = run - v;
    }
    __syncthreads();

#pragma unroll
    for (int j = 0; j < KMAX; ++j) {
        if (rs[j] != 0xFFFFFFFFu) {
            const unsigned int sub  = rs[j] & 63u;
            const unsigned int rank = rs[j] >> 6;
            recs[s0 + pre[sub] + rank] = rc[j];
        }
    }
}

// ---------------------------------------------------------------------------
// Sampler (round-5 best-measured form): 2 lanes/pt (8 channels each),
// 2 consecutive points/thread; all 24 corner loads issued before consume.
// XCD-bijective block remap keeps each XCD on a contiguous (now 15-bit-
// Morton-ordered) record slice.
// ---------------------------------------------------------------------------
__device__ __forceinline__ void load_h8(const __half* addr, float f[8])
{
    const int4 v = *(const int4*)addr;
    const __half2* h = (const __half2*)&v;
#pragma unroll
    for (int i = 0; i < 4; ++i) {
        const float2 t2 = __half22float2(h[i]);
        f[2 * i + 0] = t2.x;
        f[2 * i + 1] = t2.y;
    }
}

__global__ __launch_bounds__(256) void sample_sorted(
    const int4* __restrict__ recs, const __half* __restrict__ t,
    float* __restrict__ out, int B, int q, int r)
{
    const uint32_t bid  = blockIdx.x;
    const uint32_t xcd  = bid & 7u;
    const uint32_t slot = bid >> 3;
    const uint32_t base = (xcd < (uint32_t)r) ? xcd * (q + 1)
                                              : (uint32_t)r * (q + 1) + (xcd - r) * q;
    const uint32_t lb   = base + slot;

    const int tid = (int)(lb * 256u + threadIdx.x);
    const int pr  = tid >> 1;
    const int h   = tid & 1;
    const int p0  = pr * 2;
    if (p0 >= B) return;
    const int p1m = min(p0 + 1, B - 1);

    v4i rec[2];
    rec[0] = __builtin_nontemporal_load((const v4i*)&recs[p0]);
    rec[1] = __builtin_nontemporal_load((const v4i*)&recs[p1m]);

    float acc[2][8];
#pragma unroll
    for (int e = 0; e < 2; ++e)
#pragma unroll
        for (int k = 0; k < 8; ++k) acc[e][k] = 1.f;

#pragma unroll
    for (int pl = 0; pl < 3; ++pl) {
        const __half* pb = t + (size_t)pl * (size_t)(HW * C) + h * 8;
        float w[2][4];
        const __half* a[2][4];
#pragma unroll
        for (int e = 0; e < 2; ++e) {
            const float xv0 = __int_as_float(rec[e].x);
            const float xv1 = __int_as_float(rec[e].y);
            const float xv2 = __int_as_float(rec[e].z);
            const float gx = (pl == 2) ? xv1 : xv0;
            const float gy = (pl == 0) ? xv1 : xv2;
            const float px = (gx + 1.0f) * 0.5f * (float)(R - 1);
            const float py = (gy + 1.0f) * 0.5f * (float)(R - 1);
            const float x0f = floorf(px), y0f = floorf(py);
            const float wx = px - x0f,   wy = py - y0f;
            int x0 = (int)x0f; x0 = min(max(x0, 0), R - 1);
            int y0 = (int)y0f; y0 = min(max(y0, 0), R - 1);
            const int x1 = min(x0 + 1, R - 1);
            const int y1 = min(y0 + 1, R - 1);
            a[e][0] = pb + (size_t)(y0 * R + x0) * C;
            a[e][1] = pb + (size_t)(y0 * R + x1) * C;
            a[e][2] = pb + (size_t)(y1 * R + x0) * C;
            a[e][3] = pb + (size_t)(y1 * R + x1) * C;
            w[e][0] = (1.f - wx) * (1.f - wy);
            w[e][1] = wx * (1.f - wy);
            w[e][2] = (1.f - wx) * wy;
            w[e][3] = wx * wy;
        }
        float f[2][4][8];
#pragma unroll
        for (int c2 = 0; c2 < 4; ++c2) {
            load_h8(a[0][c2], f[0][c2]);
            load_h8(a[1][c2], f[1][c2]);
        }
#pragma unroll
        for (int e = 0; e < 2; ++e)
#pragma unroll
            for (int k = 0; k < 8; ++k)
                acc[e][k] *= f[e][0][k] * w[e][0] + f[e][1][k] * w[e][1]
                           + f[e][2][k] * w[e][2] + f[e][3][k] * w[e][3];
    }

#pragma unroll
    for (int e = 0; e < 2; ++e) {
        if (e == 0 || p0 + 1 < B) {
            float* o = out + (size_t)rec[e].w * C + h * 8;
            const v4f o0 = { acc[e][0], acc[e][1], acc[e][2], acc[e][3] };
            const v4f o1 = { acc[e][4], acc[e][5], acc[e][6], acc[e][7] };
            __builtin_nontemporal_store(o0, (v4f*)(o + 0));
            __builtin_nontemporal_store(o1, (v4f*)(o + 4));
        }
    }
}

// ============================ fallback paths ================================
__global__ __launch_bounds__(256) void transpose_chw_hwc(
    const float* __restrict__ p0, const float* __restrict__ p1,
    const float* __restrict__ p2, float* __restrict__ dst)
{
    __shared__ float lds[64 * 17];
    const int y  = blockIdx.x;
    const int x0 = blockIdx.y * 64;
    const int pl = blockIdx.z;
    const float* src = (pl == 0) ? p0 : ((pl == 1) ? p1 : p2);
    const int tid = threadIdx.x;
    const int xl  = tid & 63;
    const int c0  = tid >> 6;
#pragma unroll
    for (int i = 0; i < 4; ++i) {
        const int c = c0 * 4 + i;
        lds[xl * 17 + c] = src[c * HW + y * R + x0 + xl];
    }
    __syncthreads();
    float* dbase = dst + ((size_t)pl * HW + (size_t)(y * R + x0)) * C;
#pragma unroll
    for (int i = 0; i < 4; ++i) {
        const int j = tid + i * 256;
        dbase[j] = lds[(j >> 4) * 17 + (j & 15)];
    }
}

__global__ __launch_bounds__(256) void sample_hwc(
    const float* __restrict__ x, const float* __restrict__ t,
    float* __restrict__ out, int B)
{
    const int tid = blockIdx.x * 256 + threadIdx.x;
    const int p   = tid >> 2;
    const int cg  = tid & 3;
    if (p >= B) return;

    const float xv0 = x[(size_t)p * 3 + 0];
    const float xv1 = x[(size_t)p * 3 + 1];
    const float xv2 = x[(size_t)p * 3 + 2];
    const float gxs[3] = { xv0, xv0, xv1 };
    const float gys[3] = { xv1, xv2, xv2 };
    float4 acc = make_float4(1.f, 1.f, 1.f, 1.f);

#pragma unroll
    for (int pl = 0; pl < 3; ++pl) {
        const float gx = gxs[pl], gy = gys[pl];
        const float px = (gx + 1.0f) * 0.5f * (float)(R - 1);
        const float py = (gy + 1.0f) * 0.5f * (float)(R - 1);
        const float x0f = floorf(px), y0f = floorf(py);
        const float wx = px - x0f,   wy = py - y0f;
        int x0 = (int)x0f; x0 = min(max(x0, 0), R - 1);
        int y0 = (int)y0f; y0 = min(max(y0, 0), R - 1);
        const int x1 = min(x0 + 1, R - 1);
        const int y1 = min(y0 + 1, R - 1);

        const float* pb = t + (size_t)pl * (size_t)(HW * C) + cg * 4;
        const float4 p00 = *(const float4*)(pb + (size_t)(y0 * R + x0) * C);
        const float4 p01 = *(const float4*)(pb + (size_t)(y0 * R + x1) * C);
        const float4 p10 = *(const float4*)(pb + (size_t)(y1 * R + x0) * C);
        const float4 p11 = *(const float4*)(pb + (size_t)(y1 * R + x1) * C);

        const float w00 = (1.f - wx) * (1.f - wy);
        const float w01 = wx * (1.f - wy);
        const float w10 = (1.f - wx) * wy;
        const float w11 = wx * wy;

        float4 fv;
        fv.x = p00.x * w00 + p01.x * w01 + p10.x * w10 + p11.x * w11;
        fv.y = p00.y * w00 + p01.y * w01 + p10.y * w10 + p11.y * w11;
        fv.z = p00.z * w00 + p01.z * w01 + p10.z * w10 + p11.z * w11;
        fv.w = p00.w * w00 + p01.w * w01 + p10.w * w10 + p11.w * w11;

        acc.x *= fv.x; acc.y *= fv.y; acc.z *= fv.z; acc.w *= fv.w;
    }

    *(float4*)(out + (size_t)p * C + cg * 4) = acc;
}

__global__ __launch_bounds__(256) void sample_chw(
    const float* __restrict__ x,
    const float* __restrict__ p0, const float* __restrict__ p1,
    const float* __restrict__ p2, float* __restrict__ out, int B)
{
    const int tid = blockIdx.x * 256 + threadIdx.x;
    const int p   = tid >> 2;
    const int cg  = tid & 3;
    if (p >= B) return;
    const float xv0 = x[(size_t)p * 3 + 0];
    const float xv1 = x[(size_t)p * 3 + 1];
    const float xv2 = x[(size_t)p * 3 + 2];
    const float gxs[3] = { xv0, xv0, xv1 };
    const float gys[3] = { xv1, xv2, xv2 };
    const float* planes[3] = { p0, p1, p2 };
    float acc[4] = {1.f, 1.f, 1.f, 1.f};
#pragma unroll
    for (int pl = 0; pl < 3; ++pl) {
        const float gx = gxs[pl], gy = gys[pl];
        const float px = (gx + 1.0f) * 0.5f * (float)(R - 1);
        const float py = (gy + 1.0f) * 0.5f * (float)(R - 1);
        const float x0f = floorf(px), y0f = floorf(py);
        const float wx = px - x0f,   wy = py - y0f;
        int x0 = (int)x0f; x0 = min(max(x0, 0), R - 1);
        int y0 = (int)y0f; y0 = min(max(y0, 0), R - 1);
        const int x1 = min(x0 + 1, R - 1);
        const int y1 = min(y0 + 1, R - 1);
        const float w00 = (1.f - wx) * (1.f - wy);
        const float w01 = wx * (1.f - wy);
        const float w10 = (1.f - wx) * wy;
        const float w11 = wx * wy;
        const float* pb = planes[pl];
#pragma unroll
        for (int k = 0; k < 4; ++k) {
            const int c = cg * 4 + k;
            const float* b2 = pb + (size_t)c * HW;
            const float v00 = b2[y0 * R + x0];
            const float v01 = b2[y0 * R + x1];
            const float v10 = b2[y1 * R + x0];
            const float v11 = b2[y1 * R + x1];
            acc[k] *= v00 * w00 + v01 * w01 + v10 * w10 + v11 * w11;
        }
    }
    float* o = out + (size_t)p * C + cg * 4;
    o[0] = acc[0]; o[1] = acc[1]; o[2] = acc[2]; o[3] = acc[3];
}

// ===========================================================================
extern "C" void kernel_launch(void* const* d_in, const int* in_sizes, int n_in,
                              void* d_out, int out_size, void* d_ws, size_t ws_size,
                              hipStream_t stream) {
    const float* x  = (const float*)d_in[0];
    const float* p0 = (const float*)d_in[1];
    const float* p1 = (const float*)d_in[2];
    const float* p2 = (const float*)d_in[3];
    float* out = (float*)d_out;
    const int B = in_sizes[0] / 3;

    const size_t t_bytes    = (size_t)3 * HW * C * sizeof(__half);     // 24 MiB
    const size_t recs_bytes = (size_t)B * 16;                          // 32 MB
    const size_t cnt_bytes  = (size_t)NCNT * 4;                        // 16 KiB
    const size_t bs_bytes   = (size_t)(NB9 + 1) * 4;

    const size_t off_t      = 0;
    const size_t off_recs   = (t_bytes + 255) & ~(size_t)255;
    const size_t off_counts = (off_recs + recs_bytes + 255) & ~(size_t)255;
    const size_t off_cursor = (off_counts + cnt_bytes + 255) & ~(size_t)255;
    const size_t off_bs     = (off_cursor + cnt_bytes + 255) & ~(size_t)255;
    const size_t need_full  = off_bs + bs_bytes;

    const size_t need_fp32  = (size_t)3 * HW * C * sizeof(float);      // 48 MiB

    if (d_ws != nullptr && ws_size >= need_full) {
        __half*       t      = (__half*)((char*)d_ws + off_t);
        int4*         recs   = (int4*)((char*)d_ws + off_recs);
        unsigned int* counts = (unsigned int*)((char*)d_ws + off_counts);
        unsigned int* cursor = (unsigned int*)((char*)d_ws + off_cursor);
        unsigned int* bstart = (unsigned int*)((char*)d_ws + off_bs);

        dim3 tg(R, R / 64, 3);
        transpose_chw_hwc_h<<<tg, 256, 0, stream>>>(p0, p1, p2, t);

        hipMemsetAsync(counts, 0, cnt_bytes, stream);
        const int nblkP = (B + CHUNK - 1) / CHUNK;
        hist_pts<<<nblkP, 256, 0, stream>>>(x, counts, B);
        scan_counts<<<1, 1024, 0, stream>>>(counts, cursor, bstart);
        scatter_pts<<<nblkP, 256, 0, stream>>>(x, cursor, recs, B);
        refine_pts<<<NB9, 512, 0, stream>>>(bstart, recs);

        const int nthr2 = B;                       // 2 lanes/pt, 2 pts/thread
        const int nblk2 = (nthr2 + 255) / 256;
        const int q = nblk2 / 8, r = nblk2 % 8;
        sample_sorted<<<nblk2, 256, 0, stream>>>(recs, t, out, B, q, r);
    } else if (d_ws != nullptr && ws_size >= need_fp32) {
        float* tf = (float*)d_ws;
        dim3 tg(R, R / 64, 3);
        transpose_chw_hwc<<<tg, 256, 0, stream>>>(p0, p1, p2, tf);
        const int nthr = B * 4;
        const int nblk = (nthr + 255) / 256;
        sample_hwc<<<nblk, 256, 0, stream>>>(x, tf, out, B);
    } else {
        const int nthr = B * 4;
        const int nblk = (nthr + 255) / 256;
        sample_chw<<<nblk, 256, 0, stream>>>(x, p0, p1, p2, out, B);
    }
}

// Round 12
// 134.085 us; speedup vs baseline: 2.8009x; 1.2388x over previous
//
#include <hip/hip_runtime.h>
#include <hip/hip_fp16.h>
#include <cstdint>
#include <cstddef>

constexpr int R  = 512;
constexpr int C  = 16;
constexpr int HW = R * R;

constexpr int NB9   = 512;    // coarse bins: 3 bits/axis (64px cells)
constexpr int NPART = 8;      // XCD partitions for coarse counters
constexpr int NCNT  = NB9 * NPART;
constexpr int CHUNK = 4096;   // pts/block in hist/scatter
constexpr int KMAX  = 16;     // refine: recs per thread (cap 8192 per coarse bin)

typedef float v4f __attribute__((ext_vector_type(4)));
typedef int   v4i __attribute__((ext_vector_type(4)));

// ---- unified, bit-exact coordinate helpers ----------
__device__ __forceinline__ float tcoord(float g) {
    return __fmul_rn(__fadd_rn(g, 1.0f), 255.5f);   // bit-exact == ((g+1)*0.5f)*511
}
__device__ __forceinline__ int cell512(float g) {
    const int i = (int)tcoord(g);
    return min(max(i, 0), R - 1);
}
__device__ __forceinline__ uint32_t mortonN(int a, int b, int c, int nb) {
    uint32_t k = 0;
#pragma unroll
    for (int i = 0; i < 5; ++i) {
        if (i < nb) {
            k |= ((uint32_t)((a >> i) & 1)) << (3 * i + 2);
            k |= ((uint32_t)((b >> i) & 1)) << (3 * i + 1);
            k |= ((uint32_t)((c >> i) & 1)) << (3 * i + 0);
        }
    }
    return k;
}
__device__ __forceinline__ uint32_t key9(float a, float b, float c) {
    return mortonN(cell512(a) >> 6, cell512(b) >> 6, cell512(c) >> 6, 3);
}

// ---- forced-MLP gather primitives (inline asm, SADDR + 32-bit voffset) ----
__device__ __forceinline__ v4i gload16(const void* base, uint32_t voff) {
    v4i r;
    asm volatile("global_load_dwordx4 %0, %1, %2"
                 : "=&v"(r) : "v"(voff), "s"(base));
    return r;
}
#define VMWAIT(N) do { \
    asm volatile("s_waitcnt vmcnt(" #N ")" ::: "memory"); \
    __builtin_amdgcn_sched_barrier(0); \
} while (0)

// ---------------------------------------------------------------------------
// Transpose (C,H,W) fp32 -> (H,W,C) fp16 (interleaved 32B texels).
// ---------------------------------------------------------------------------
__global__ __launch_bounds__(256) void transpose_chw_hwc_h(
    const float* __restrict__ p0, const float* __restrict__ p1,
    const float* __restrict__ p2, __half* __restrict__ dst)
{
    __shared__ float lds[64 * 17];
    const int y  = blockIdx.x;
    const int x0 = blockIdx.y * 64;
    const int pl = blockIdx.z;
    const float* src = (pl == 0) ? p0 : ((pl == 1) ? p1 : p2);
    const int tid = threadIdx.x;
    const int xl  = tid & 63;
    const int c0  = tid >> 6;
#pragma unroll
    for (int i = 0; i < 4; ++i) {
        const int c = c0 * 4 + i;
        lds[xl * 17 + c] = src[c * HW + y * R + x0 + xl];
    }
    __syncthreads();
    __half2* dbase = (__half2*)(dst + ((size_t)pl * HW + (size_t)(y * R + x0)) * C);
#pragma unroll
    for (int i = 0; i < 2; ++i) {
        const int j  = tid + i * 256;
        const int e0 = 2 * j;
        const float a = lds[(e0 >> 4) * 17 + (e0 & 15)];
        const float b = lds[(e0 >> 4) * 17 + ((e0 & 15) + 1)];
        dbase[j] = __floats2half2_rn(a, b);
    }
}

// ---------------------------------------------------------------------------
// Coarse histogram (9-bit) with LDS aggregation.
// ---------------------------------------------------------------------------
__global__ __launch_bounds__(256) void hist_pts(
    const float* __restrict__ x, unsigned int* __restrict__ counts, int B)
{
    __shared__ unsigned int h[NB9];
    const int tid = threadIdx.x;
    for (int i = tid; i < NB9; i += 256) h[i] = 0;
    __syncthreads();
    const int start = blockIdx.x * CHUNK;
#pragma unroll
    for (int j = 0; j < CHUNK / 256; ++j) {
        const int i = start + j * 256 + tid;
        if (i < B) {
            const float a = x[(size_t)i * 3 + 0];
            const float b = x[(size_t)i * 3 + 1];
            const float c = x[(size_t)i * 3 + 2];
            atomicAdd(&h[key9(a, b, c)], 1u);
        }
    }
    __syncthreads();
    unsigned int* cb = counts + (blockIdx.x & (NPART - 1)) * NB9;
    for (int i = tid; i < NB9; i += 256) {
        const unsigned int c = h[i];
        if (c) atomicAdd(&cb[i], c);
    }
}

// Scan 4096 coarse counters in LOGICAL (key,part) order (records bin-major);
// counters part-major in memory. Emits binStart[key] for refine.
__global__ __launch_bounds__(1024) void scan_counts(
    const unsigned int* __restrict__ counts, unsigned int* __restrict__ cursor,
    unsigned int* __restrict__ binStart)
{
    __shared__ unsigned int s[1024];
    const int t = threadIdx.x;
    unsigned int v[4];
    unsigned int sum = 0;
#pragma unroll
    for (int i = 0; i < 4; ++i) {
        const int L = t * 4 + i;            // logical = key*NPART + part
        const int key = L >> 3, part = L & 7;
        v[i] = counts[part * NB9 + key];
        sum += v[i];
    }
    unsigned int run = 0;
#pragma unroll
    for (int i = 0; i < 4; ++i) { const unsigned int tmp = v[i]; v[i] = run; run += tmp; }
    s[t] = sum;
    __syncthreads();
    unsigned int incl = sum;
    for (int off = 1; off < 1024; off <<= 1) {
        const unsigned int u = (t >= off) ? s[t - off] : 0u;
        __syncthreads();
        incl += u;
        s[t] = incl;
        __syncthreads();
    }
    const unsigned int excl = incl - sum;
#pragma unroll
    for (int i = 0; i < 4; ++i) {
        const int L = t * 4 + i;
        const int key = L >> 3, part = L & 7;
        cursor[part * NB9 + key] = excl + v[i];
        if (part == 0) binStart[key] = excl + v[i];
    }
    if (t == 1023) binStart[NB9] = incl;    // = B
}

// ---------------------------------------------------------------------------
// Coarse scatter: block-local counting sort (bin-sorted, run-coalesced writes).
// ---------------------------------------------------------------------------
__global__ __launch_bounds__(256) void scatter_pts(
    const float* __restrict__ x, unsigned int* __restrict__ cursor,
    int4* __restrict__ recs, int B)
{
    __shared__ unsigned int h[NB9];
    __shared__ unsigned int gbase[NB9];
    __shared__ unsigned int lpre[NB9];
    __shared__ unsigned int lcur[NB9];
    __shared__ int4 buf[CHUNK];
    __shared__ unsigned short binOf[CHUNK];

    const int tid   = threadIdx.x;
    const int start = blockIdx.x * CHUNK;
    const int V     = min(CHUNK, B - start);

    for (int i = tid; i < NB9; i += 256) h[i] = 0;
    __syncthreads();

    float pa[CHUNK / 256], pb_[CHUNK / 256], pc[CHUNK / 256];
    unsigned int pk[CHUNK / 256];
#pragma unroll
    for (int j = 0; j < CHUNK / 256; ++j) {
        const int i = start + j * 256 + tid;
        pk[j] = 0xFFFFFFFFu;
        if (i < B) {
            pa[j] = x[(size_t)i * 3 + 0];
            pb_[j] = x[(size_t)i * 3 + 1];
            pc[j] = x[(size_t)i * 3 + 2];
            pk[j] = key9(pa[j], pb_[j], pc[j]);
            atomicAdd(&h[pk[j]], 1u);
        }
    }
    __syncthreads();

    unsigned int* cb = cursor + (blockIdx.x & (NPART - 1)) * NB9;
    for (int b = tid; b < NB9; b += 256) {
        const unsigned int c = h[b];
        gbase[b] = c ? atomicAdd(&cb[b], c) : 0u;
    }
    if (tid < 64) {
        unsigned int loc[8];
        unsigned int tot = 0;
#pragma unroll
        for (int j = 0; j < 8; ++j) { loc[j] = h[tid * 8 + j]; tot += loc[j]; }
        unsigned int run = tot;
#pragma unroll
        for (int d = 1; d < 64; d <<= 1) {
            const unsigned int u = __shfl_up(run, (unsigned)d, 64);
            if (tid >= d) run += u;
        }
        unsigned int excl = run - tot;
#pragma unroll
        for (int j = 0; j < 8; ++j) { lpre[tid * 8 + j] = excl; excl += loc[j]; }
    }
    __syncthreads();
    for (int b = tid; b < NB9; b += 256) lcur[b] = lpre[b];
    __syncthreads();

#pragma unroll
    for (int j = 0; j < CHUNK / 256; ++j) {
        if (pk[j] != 0xFFFFFFFFu) {
            const int i = start + j * 256 + tid;
            const unsigned int rk = atomicAdd(&lcur[pk[j]], 1u);
            buf[rk] = make_int4(__float_as_int(pa[j]), __float_as_int(pb_[j]),
                                __float_as_int(pc[j]), i);
            binOf[rk] = (unsigned short)pk[j];
        }
    }
    __syncthreads();

    for (int idx = tid; idx < V; idx += 256) {
        const int4 rc = buf[idx];
        const int  k  = binOf[idx];
        const unsigned int dest = gbase[k] + ((unsigned int)idx - lpre[k]);
        const v4i rv = { rc.x, rc.y, rc.z, rc.w };
        __builtin_nontemporal_store(rv, (v4i*)&recs[dest]);
    }
}

// ---------------------------------------------------------------------------
// Refine: in-place permutation of each coarse bin's records by the 6 finer
// Morton bits -> overall 15-bit order (16px cells). Records held in
// registers across the barrier; one block per coarse bin.
// ---------------------------------------------------------------------------
__global__ __launch_bounds__(512) void refine_pts(
    const unsigned int* __restrict__ binStart, int4* __restrict__ recs)
{
    __shared__ unsigned int h[64];
    __shared__ unsigned int pre[64];
    const int k = blockIdx.x;
    const unsigned int s0 = binStart[k];
    const unsigned int s1 = binStart[k + 1];
    const int tid = threadIdx.x;
    if (tid < 64) h[tid] = 0;
    __syncthreads();

    int4 rc[KMAX];
    unsigned int rs[KMAX];                  // (rank<<6)|sub
#pragma unroll
    for (int j = 0; j < KMAX; ++j) {
        const unsigned int idx = s0 + (unsigned)tid + (unsigned)j * 512u;
        rs[j] = 0xFFFFFFFFu;
        if (idx < s1) {
            rc[j] = recs[idx];
            const int c0 = cell512(__int_as_float(rc[j].x)) >> 4;
            const int c1 = cell512(__int_as_float(rc[j].y)) >> 4;
            const int c2 = cell512(__int_as_float(rc[j].z)) >> 4;
            const unsigned int sub = mortonN(c0, c1, c2, 5) & 63u;
            const unsigned int rank = atomicAdd(&h[sub], 1u);
            rs[j] = (rank << 6) | sub;
        }
    }
    __syncthreads();

    if (tid < 64) {
        const unsigned int v = h[tid];
        unsigned int run = v;
#pragma unroll
        for (int d = 1; d < 64; d <<= 1) {
            const unsigned int u = __shfl_up(run, (unsigned)d, 64);
            if (tid >= d) run += u;
        }
        pre[tid] = run - v;
    }
    __syncthreads();

#pragma unroll
    for (int j = 0; j < KMAX; ++j) {
        if (rs[j] != 0xFFFFFFFFu) {
            const unsigned int sub  = rs[j] & 63u;
            const unsigned int rank = rs[j] >> 6;
            recs[s0 + pre[sub] + rank] = rc[j];
        }
    }
}

// ---------------------------------------------------------------------------
// Sampler with FORCED 24-deep MLP: 24 inline-asm global_load_dwordx4 issued
// back-to-back (compiler cannot sink them), consumed per-plane behind counted
// s_waitcnt vmcnt(16/8/0), each fenced with sched_barrier(0) (guide rule #18).
// 2 lanes/pt (8 channels each), 2 consecutive points/thread.
// ---------------------------------------------------------------------------
__global__ __launch_bounds__(256) void sample_sorted(
    const int4* __restrict__ recs, const __half* __restrict__ t,
    float* __restrict__ out, int B, int q, int r)
{
    const uint32_t bid  = blockIdx.x;
    const uint32_t xcd  = bid & 7u;
    const uint32_t slot = bid >> 3;
    const uint32_t base = (xcd < (uint32_t)r) ? xcd * (q + 1)
                                              : (uint32_t)r * (q + 1) + (xcd - r) * q;
    const uint32_t lb   = base + slot;

    const int tid = (int)(lb * 256u + threadIdx.x);
    const int pr  = tid >> 1;
    const int h   = tid & 1;
    const int p0  = pr * 2;
    if (p0 >= B) return;
    const int p1m = min(p0 + 1, B - 1);

    v4i rec[2];
    rec[0] = __builtin_nontemporal_load((const v4i*)&recs[p0]);
    rec[1] = __builtin_nontemporal_load((const v4i*)&recs[p1m]);

    // ---- coordinate math: weights + 24 byte offsets (32-bit) ----
    float w[2][3][4];
    uint32_t off[2][3][4];
    const uint32_t hofs = (uint32_t)h * 16u;
#pragma unroll
    for (int e = 0; e < 2; ++e) {
        const float xv0 = __int_as_float(rec[e].x);
        const float xv1 = __int_as_float(rec[e].y);
        const float xv2 = __int_as_float(rec[e].z);
#pragma unroll
        for (int pl = 0; pl < 3; ++pl) {
            const float gx = (pl == 2) ? xv1 : xv0;
            const float gy = (pl == 0) ? xv1 : xv2;
            const float px = (gx + 1.0f) * 0.5f * (float)(R - 1);
            const float py = (gy + 1.0f) * 0.5f * (float)(R - 1);
            const float x0f = floorf(px), y0f = floorf(py);
            const float wx = px - x0f,   wy = py - y0f;
            int x0 = (int)x0f; x0 = min(max(x0, 0), R - 1);
            int y0 = (int)y0f; y0 = min(max(y0, 0), R - 1);
            const int x1 = min(x0 + 1, R - 1);
            const int y1 = min(y0 + 1, R - 1);
            const uint32_t r0 = ((uint32_t)(y0 * R) + (uint32_t)x0) * 32u + hofs;
            const uint32_t r1 = ((uint32_t)(y0 * R) + (uint32_t)x1) * 32u + hofs;
            const uint32_t r2 = ((uint32_t)(y1 * R) + (uint32_t)x0) * 32u + hofs;
            const uint32_t r3 = ((uint32_t)(y1 * R) + (uint32_t)x1) * 32u + hofs;
            off[e][pl][0] = r0; off[e][pl][1] = r1;
            off[e][pl][2] = r2; off[e][pl][3] = r3;
            w[e][pl][0] = (1.f - wx) * (1.f - wy);
            w[e][pl][1] = wx * (1.f - wy);
            w[e][pl][2] = (1.f - wx) * wy;
            w[e][pl][3] = wx * wy;
        }
    }

    // ---- issue ALL 24 loads (volatile asm: order pinned, cannot sink) ----
    v4i raw[3][2][4];
#pragma unroll
    for (int pl = 0; pl < 3; ++pl) {
        const void* pb = (const char*)t + (size_t)pl * ((size_t)HW * C * 2);
#pragma unroll
        for (int e = 0; e < 2; ++e)
#pragma unroll
            for (int c2 = 0; c2 < 4; ++c2)
                raw[pl][e][c2] = gload16(pb, off[e][pl][c2]);
    }

    float acc[2][8];
#pragma unroll
    for (int e = 0; e < 2; ++e)
#pragma unroll
        for (int k = 0; k < 8; ++k) acc[e][k] = 1.f;

    // ---- consume plane-by-plane behind counted waits ----
#pragma unroll
    for (int pl = 0; pl < 3; ++pl) {
        if (pl == 0) VMWAIT(16);
        else if (pl == 1) VMWAIT(8);
        else VMWAIT(0);
#pragma unroll
        for (int e = 0; e < 2; ++e) {
            const __half2* f0 = (const __half2*)&raw[pl][e][0];
            const __half2* f1 = (const __half2*)&raw[pl][e][1];
            const __half2* f2 = (const __half2*)&raw[pl][e][2];
            const __half2* f3 = (const __half2*)&raw[pl][e][3];
            const float w00 = w[e][pl][0], w01 = w[e][pl][1];
            const float w10 = w[e][pl][2], w11 = w[e][pl][3];
#pragma unroll
            for (int i2 = 0; i2 < 4; ++i2) {
                const float2 a0 = __half22float2(f0[i2]);
                const float2 a1 = __half22float2(f1[i2]);
                const float2 a2 = __half22float2(f2[i2]);
                const float2 a3 = __half22float2(f3[i2]);
                acc[e][2 * i2 + 0] *= a0.x * w00 + a1.x * w01 + a2.x * w10 + a3.x * w11;
                acc[e][2 * i2 + 1] *= a0.y * w00 + a1.y * w01 + a2.y * w10 + a3.y * w11;
            }
        }
    }

#pragma unroll
    for (int e = 0; e < 2; ++e) {
        if (e == 0 || p0 + 1 < B) {
            float* o = out + (size_t)rec[e].w * C + h * 8;
            const v4f o0 = { acc[e][0], acc[e][1], acc[e][2], acc[e][3] };
            const v4f o1 = { acc[e][4], acc[e][5], acc[e][6], acc[e][7] };
            __builtin_nontemporal_store(o0, (v4f*)(o + 0));
            __builtin_nontemporal_store(o1, (v4f*)(o + 4));
        }
    }
}

// ============================ fallback paths ================================
__global__ __launch_bounds__(256) void transpose_chw_hwc(
    const float* __restrict__ p0, const float* __restrict__ p1,
    const float* __restrict__ p2, float* __restrict__ dst)
{
    __shared__ float lds[64 * 17];
    const int y  = blockIdx.x;
    const int x0 = blockIdx.y * 64;
    const int pl = blockIdx.z;
    const float* src = (pl == 0) ? p0 : ((pl == 1) ? p1 : p2);
    const int tid = threadIdx.x;
    const int xl  = tid & 63;
    const int c0  = tid >> 6;
#pragma unroll
    for (int i = 0; i < 4; ++i) {
        const int c = c0 * 4 + i;
        lds[xl * 17 + c] = src[c * HW + y * R + x0 + xl];
    }
    __syncthreads();
    float* dbase = dst + ((size_t)pl * HW + (size_t)(y * R + x0)) * C;
#pragma unroll
    for (int i = 0; i < 4; ++i) {
        const int j = tid + i * 256;
        dbase[j] = lds[(j >> 4) * 17 + (j & 15)];
    }
}

__global__ __launch_bounds__(256) void sample_hwc(
    const float* __restrict__ x, const float* __restrict__ t,
    float* __restrict__ out, int B)
{
    const int tid = blockIdx.x * 256 + threadIdx.x;
    const int p   = tid >> 2;
    const int cg  = tid & 3;
    if (p >= B) return;

    const float xv0 = x[(size_t)p * 3 + 0];
    const float xv1 = x[(size_t)p * 3 + 1];
    const float xv2 = x[(size_t)p * 3 + 2];
    const float gxs[3] = { xv0, xv0, xv1 };
    const float gys[3] = { xv1, xv2, xv2 };
    float4 acc = make_float4(1.f, 1.f, 1.f, 1.f);

#pragma unroll
    for (int pl = 0; pl < 3; ++pl) {
        const float gx = gxs[pl], gy = gys[pl];
        const float px = (gx + 1.0f) * 0.5f * (float)(R - 1);
        const float py = (gy + 1.0f) * 0.5f * (float)(R - 1);
        const float x0f = floorf(px), y0f = floorf(py);
        const float wx = px - x0f,   wy = py - y0f;
        int x0 = (int)x0f; x0 = min(max(x0, 0), R - 1);
        int y0 = (int)y0f; y0 = min(max(y0, 0), R - 1);
        const int x1 = min(x0 + 1, R - 1);
        const int y1 = min(y0 + 1, R - 1);

        const float* pb = t + (size_t)pl * (size_t)(HW * C) + cg * 4;
        const float4 p00 = *(const float4*)(pb + (size_t)(y0 * R + x0) * C);
        const float4 p01 = *(const float4*)(pb + (size_t)(y0 * R + x1) * C);
        const float4 p10 = *(const float4*)(pb + (size_t)(y1 * R + x0) * C);
        const float4 p11 = *(const float4*)(pb + (size_t)(y1 * R + x1) * C);

        const float w00 = (1.f - wx) * (1.f - wy);
        const float w01 = wx * (1.f - wy);
        const float w10 = (1.f - wx) * wy;
        const float w11 = wx * wy;

        float4 fv;
        fv.x = p00.x * w00 + p01.x * w01 + p10.x * w10 + p11.x * w11;
        fv.y = p00.y * w00 + p01.y * w01 + p10.y * w10 + p11.y * w11;
        fv.z = p00.z * w00 + p01.z * w01 + p10.z * w10 + p11.z * w11;
        fv.w = p00.w * w00 + p01.w * w01 + p10.w * w10 + p11.w * w11;

        acc.x *= fv.x; acc.y *= fv.y; acc.z *= fv.z; acc.w *= fv.w;
    }

    *(float4*)(out + (size_t)p * C + cg * 4) = acc;
}

__global__ __launch_bounds__(256) void sample_chw(
    const float* __restrict__ x,
    const float* __restrict__ p0, const float* __restrict__ p1,
    const float* __restrict__ p2, float* __restrict__ out, int B)
{
    const int tid = blockIdx.x * 256 + threadIdx.x;
    const int p   = tid >> 2;
    const int cg  = tid & 3;
    if (p >= B) return;
    const float xv0 = x[(size_t)p * 3 + 0];
    const float xv1 = x[(size_t)p * 3 + 1];
    const float xv2 = x[(size_t)p * 3 + 2];
    const float gxs[3] = { xv0, xv0, xv1 };
    const float gys[3] = { xv1, xv2, xv2 };
    const float* planes[3] = { p0, p1, p2 };
    float acc[4] = {1.f, 1.f, 1.f, 1.f};
#pragma unroll
    for (int pl = 0; pl < 3; ++pl) {
        const float gx = gxs[pl], gy = gys[pl];
        const float px = (gx + 1.0f) * 0.5f * (float)(R - 1);
        const float py = (gy + 1.0f) * 0.5f * (float)(R - 1);
        const float x0f = floorf(px), y0f = floorf(py);
        const float wx = px - x0f,   wy = py - y0f;
        int x0 = (int)x0f; x0 = min(max(x0, 0), R - 1);
        int y0 = (int)y0f; y0 = min(max(y0, 0), R - 1);
        const int x1 = min(x0 + 1, R - 1);
        const int y1 = min(y0 + 1, R - 1);
        const float w00 = (1.f - wx) * (1.f - wy);
        const float w01 = wx * (1.f - wy);
        const float w10 = (1.f - wx) * wy;
        const float w11 = wx * wy;
        const float* pb = planes[pl];
#pragma unroll
        for (int k = 0; k < 4; ++k) {
            const int c = cg * 4 + k;
            const float* b2 = pb + (size_t)c * HW;
            const float v00 = b2[y0 * R + x0];
            const float v01 = b2[y0 * R + x1];
            const float v10 = b2[y1 * R + x0];
            const float v11 = b2[y1 * R + x1];
            acc[k] *= v00 * w00 + v01 * w01 + v10 * w10 + v11 * w11;
        }
    }
    float* o = out + (size_t)p * C + cg * 4;
    o[0] = acc[0]; o[1] = acc[1]; o[2] = acc[2]; o[3] = acc[3];
}

// ===========================================================================
extern "C" void kernel_launch(void* const* d_in, const int* in_sizes, int n_in,
                              void* d_out, int out_size, void* d_ws, size_t ws_size,
                              hipStream_t stream) {
    const float* x  = (const float*)d_in[0];
    const float* p0 = (const float*)d_in[1];
    const float* p1 = (const float*)d_in[2];
    const float* p2 = (const float*)d_in[3];
    float* out = (float*)d_out;
    const int B = in_sizes[0] / 3;

    const size_t t_bytes    = (size_t)3 * HW * C * sizeof(__half);     // 24 MiB
    const size_t recs_bytes = (size_t)B * 16;                          // 32 MB
    const size_t cnt_bytes  = (size_t)NCNT * 4;                        // 16 KiB
    const size_t bs_bytes   = (size_t)(NB9 + 1) * 4;

    const size_t off_t      = 0;
    const size_t off_recs   = (t_bytes + 255) & ~(size_t)255;
    const size_t off_counts = (off_recs + recs_bytes + 255) & ~(size_t)255;
    const size_t off_cursor = (off_counts + cnt_bytes + 255) & ~(size_t)255;
    const size_t off_bs     = (off_cursor + cnt_bytes + 255) & ~(size_t)255;
    const size_t need_full  = off_bs + bs_bytes;

    const size_t need_fp32  = (size_t)3 * HW * C * sizeof(float);      // 48 MiB

    if (d_ws != nullptr && ws_size >= need_full) {
        __half*       t      = (__half*)((char*)d_ws + off_t);
        int4*         recs   = (int4*)((char*)d_ws + off_recs);
        unsigned int* counts = (unsigned int*)((char*)d_ws + off_counts);
        unsigned int* cursor = (unsigned int*)((char*)d_ws + off_cursor);
        unsigned int* bstart = (unsigned int*)((char*)d_ws + off_bs);

        dim3 tg(R, R / 64, 3);
        transpose_chw_hwc_h<<<tg, 256, 0, stream>>>(p0, p1, p2, t);

        hipMemsetAsync(counts, 0, cnt_bytes, stream);
        const int nblkP = (B + CHUNK - 1) / CHUNK;
        hist_pts<<<nblkP, 256, 0, stream>>>(x, counts, B);
        scan_counts<<<1, 1024, 0, stream>>>(counts, cursor, bstart);
        scatter_pts<<<nblkP, 256, 0, stream>>>(x, cursor, recs, B);
        refine_pts<<<NB9, 512, 0, stream>>>(bstart, recs);

        const int nthr2 = B;                       // 2 lanes/pt, 2 pts/thread
        const int nblk2 = (nthr2 + 255) / 256;
        const int q = nblk2 / 8, r = nblk2 % 8;
        sample_sorted<<<nblk2, 256, 0, stream>>>(recs, t, out, B, q, r);
    } else if (d_ws != nullptr && ws_size >= need_fp32) {
        float* tf = (float*)d_ws;
        dim3 tg(R, R / 64, 3);
        transpose_chw_hwc<<<tg, 256, 0, stream>>>(p0, p1, p2, tf);
        const int nthr = B * 4;
        const int nblk = (nthr + 255) / 256;
        sample_hwc<<<nblk, 256, 0, stream>>>(x, tf, out, B);
    } else {
        const int nthr = B * 4;
        const int nblk = (nthr + 255) / 256;
        sample_chw<<<nblk, 256, 0, stream>>>(x, p0, p1, p2, out, B);
    }
}

// Round 13
// 133.867 us; speedup vs baseline: 2.8055x; 1.0016x over previous
//
#include <hip/hip_runtime.h>
#include <hip/hip_fp16.h>
#include <cstdint>
#include <cstddef>

constexpr int R  = 512;
constexpr int C  = 16;
constexpr int HW = R * R;

constexpr int NB9   = 512;    // coarse bins: 3 bits/axis (64px cells)
constexpr int NPART = 8;      // XCD partitions for coarse counters
constexpr int NCNT  = NB9 * NPART;
constexpr int CHUNK = 4096;   // pts/block in hist/scatter
constexpr int KMAX  = 16;     // refine: recs per thread (cap 8192 per coarse bin)

typedef float v4f __attribute__((ext_vector_type(4)));
typedef int   v4i __attribute__((ext_vector_type(4)));

// ---- unified, bit-exact coordinate helpers ----------
__device__ __forceinline__ float tcoord(float g) {
    return __fmul_rn(__fadd_rn(g, 1.0f), 255.5f);   // bit-exact == ((g+1)*0.5f)*511
}
__device__ __forceinline__ int cell512(float g) {
    const int i = (int)tcoord(g);
    return min(max(i, 0), R - 1);
}
__device__ __forceinline__ uint32_t mortonN(int a, int b, int c, int nb) {
    uint32_t k = 0;
#pragma unroll
    for (int i = 0; i < 5; ++i) {
        if (i < nb) {
            k |= ((uint32_t)((a >> i) & 1)) << (3 * i + 2);
            k |= ((uint32_t)((b >> i) & 1)) << (3 * i + 1);
            k |= ((uint32_t)((c >> i) & 1)) << (3 * i + 0);
        }
    }
    return k;
}
__device__ __forceinline__ uint32_t key9(float a, float b, float c) {
    return mortonN(cell512(a) >> 6, cell512(b) >> 6, cell512(c) >> 6, 3);
}

// ---- forced-MLP gather primitives (inline asm, SADDR + 32-bit voffset) ----
__device__ __forceinline__ v4i gload16(const void* base, uint32_t voff) {
    v4i r;
    asm volatile("global_load_dwordx4 %0, %1, %2"
                 : "=&v"(r) : "v"(voff), "s"(base));
    return r;
}
#define VMWAIT(N) do { \
    asm volatile("s_waitcnt vmcnt(" #N ")" ::: "memory"); \
    __builtin_amdgcn_sched_barrier(0); \
} while (0)

// ---------------------------------------------------------------------------
// Transpose (C,H,W) fp32 -> (H,W,C) fp16 (interleaved 32B texels).
// ---------------------------------------------------------------------------
__global__ __launch_bounds__(256) void transpose_chw_hwc_h(
    const float* __restrict__ p0, const float* __restrict__ p1,
    const float* __restrict__ p2, __half* __restrict__ dst)
{
    __shared__ float lds[64 * 17];
    const int y  = blockIdx.x;
    const int x0 = blockIdx.y * 64;
    const int pl = blockIdx.z;
    const float* src = (pl == 0) ? p0 : ((pl == 1) ? p1 : p2);
    const int tid = threadIdx.x;
    const int xl  = tid & 63;
    const int c0  = tid >> 6;
#pragma unroll
    for (int i = 0; i < 4; ++i) {
        const int c = c0 * 4 + i;
        lds[xl * 17 + c] = src[c * HW + y * R + x0 + xl];
    }
    __syncthreads();
    __half2* dbase = (__half2*)(dst + ((size_t)pl * HW + (size_t)(y * R + x0)) * C);
#pragma unroll
    for (int i = 0; i < 2; ++i) {
        const int j  = tid + i * 256;
        const int e0 = 2 * j;
        const float a = lds[(e0 >> 4) * 17 + (e0 & 15)];
        const float b = lds[(e0 >> 4) * 17 + ((e0 & 15) + 1)];
        dbase[j] = __floats2half2_rn(a, b);
    }
}

// ---------------------------------------------------------------------------
// Coarse histogram (9-bit) with LDS aggregation.
// ---------------------------------------------------------------------------
__global__ __launch_bounds__(256) void hist_pts(
    const float* __restrict__ x, unsigned int* __restrict__ counts, int B)
{
    __shared__ unsigned int h[NB9];
    const int tid = threadIdx.x;
    for (int i = tid; i < NB9; i += 256) h[i] = 0;
    __syncthreads();
    const int start = blockIdx.x * CHUNK;
#pragma unroll
    for (int j = 0; j < CHUNK / 256; ++j) {
        const int i = start + j * 256 + tid;
        if (i < B) {
            const float a = x[(size_t)i * 3 + 0];
            const float b = x[(size_t)i * 3 + 1];
            const float c = x[(size_t)i * 3 + 2];
            atomicAdd(&h[key9(a, b, c)], 1u);
        }
    }
    __syncthreads();
    unsigned int* cb = counts + (blockIdx.x & (NPART - 1)) * NB9;
    for (int i = tid; i < NB9; i += 256) {
        const unsigned int c = h[i];
        if (c) atomicAdd(&cb[i], c);
    }
}

// Scan 4096 coarse counters in LOGICAL (key,part) order (records bin-major);
// counters part-major in memory. Emits binStart[key] for refine.
__global__ __launch_bounds__(1024) void scan_counts(
    const unsigned int* __restrict__ counts, unsigned int* __restrict__ cursor,
    unsigned int* __restrict__ binStart)
{
    __shared__ unsigned int s[1024];
    const int t = threadIdx.x;
    unsigned int v[4];
    unsigned int sum = 0;
#pragma unroll
    for (int i = 0; i < 4; ++i) {
        const int L = t * 4 + i;            // logical = key*NPART + part
        const int key = L >> 3, part = L & 7;
        v[i] = counts[part * NB9 + key];
        sum += v[i];
    }
    unsigned int run = 0;
#pragma unroll
    for (int i = 0; i < 4; ++i) { const unsigned int tmp = v[i]; v[i] = run; run += tmp; }
    s[t] = sum;
    __syncthreads();
    unsigned int incl = sum;
    for (int off = 1; off < 1024; off <<= 1) {
        const unsigned int u = (t >= off) ? s[t - off] : 0u;
        __syncthreads();
        incl += u;
        s[t] = incl;
        __syncthreads();
    }
    const unsigned int excl = incl - sum;
#pragma unroll
    for (int i = 0; i < 4; ++i) {
        const int L = t * 4 + i;
        const int key = L >> 3, part = L & 7;
        cursor[part * NB9 + key] = excl + v[i];
        if (part == 0) binStart[key] = excl + v[i];
    }
    if (t == 1023) binStart[NB9] = incl;    // = B
}

// ---------------------------------------------------------------------------
// Coarse scatter: block-local counting sort (bin-sorted, run-coalesced writes).
// ---------------------------------------------------------------------------
__global__ __launch_bounds__(256) void scatter_pts(
    const float* __restrict__ x, unsigned int* __restrict__ cursor,
    int4* __restrict__ recs, int B)
{
    __shared__ unsigned int h[NB9];
    __shared__ unsigned int gbase[NB9];
    __shared__ unsigned int lpre[NB9];
    __shared__ unsigned int lcur[NB9];
    __shared__ int4 buf[CHUNK];
    __shared__ unsigned short binOf[CHUNK];

    const int tid   = threadIdx.x;
    const int start = blockIdx.x * CHUNK;
    const int V     = min(CHUNK, B - start);

    for (int i = tid; i < NB9; i += 256) h[i] = 0;
    __syncthreads();

    float pa[CHUNK / 256], pb_[CHUNK / 256], pc[CHUNK / 256];
    unsigned int pk[CHUNK / 256];
#pragma unroll
    for (int j = 0; j < CHUNK / 256; ++j) {
        const int i = start + j * 256 + tid;
        pk[j] = 0xFFFFFFFFu;
        if (i < B) {
            pa[j] = x[(size_t)i * 3 + 0];
            pb_[j] = x[(size_t)i * 3 + 1];
            pc[j] = x[(size_t)i * 3 + 2];
            pk[j] = key9(pa[j], pb_[j], pc[j]);
            atomicAdd(&h[pk[j]], 1u);
        }
    }
    __syncthreads();

    unsigned int* cb = cursor + (blockIdx.x & (NPART - 1)) * NB9;
    for (int b = tid; b < NB9; b += 256) {
        const unsigned int c = h[b];
        gbase[b] = c ? atomicAdd(&cb[b], c) : 0u;
    }
    if (tid < 64) {
        unsigned int loc[8];
        unsigned int tot = 0;
#pragma unroll
        for (int j = 0; j < 8; ++j) { loc[j] = h[tid * 8 + j]; tot += loc[j]; }
        unsigned int run = tot;
#pragma unroll
        for (int d = 1; d < 64; d <<= 1) {
            const unsigned int u = __shfl_up(run, (unsigned)d, 64);
            if (tid >= d) run += u;
        }
        unsigned int excl = run - tot;
#pragma unroll
        for (int j = 0; j < 8; ++j) { lpre[tid * 8 + j] = excl; excl += loc[j]; }
    }
    __syncthreads();
    for (int b = tid; b < NB9; b += 256) lcur[b] = lpre[b];
    __syncthreads();

#pragma unroll
    for (int j = 0; j < CHUNK / 256; ++j) {
        if (pk[j] != 0xFFFFFFFFu) {
            const int i = start + j * 256 + tid;
            const unsigned int rk = atomicAdd(&lcur[pk[j]], 1u);
            buf[rk] = make_int4(__float_as_int(pa[j]), __float_as_int(pb_[j]),
                                __float_as_int(pc[j]), i);
            binOf[rk] = (unsigned short)pk[j];
        }
    }
    __syncthreads();

    for (int idx = tid; idx < V; idx += 256) {
        const int4 rc = buf[idx];
        const int  k  = binOf[idx];
        const unsigned int dest = gbase[k] + ((unsigned int)idx - lpre[k]);
        const v4i rv = { rc.x, rc.y, rc.z, rc.w };
        __builtin_nontemporal_store(rv, (v4i*)&recs[dest]);
    }
}

// ---------------------------------------------------------------------------
// Refine: in-place permutation of each coarse bin's records by the 6 finer
// Morton bits -> overall 15-bit order (16px cells). Records held in
// registers across the barrier; one block per coarse bin.
// ---------------------------------------------------------------------------
__global__ __launch_bounds__(512) void refine_pts(
    const unsigned int* __restrict__ binStart, int4* __restrict__ recs)
{
    __shared__ unsigned int h[64];
    __shared__ unsigned int pre[64];
    const int k = blockIdx.x;
    const unsigned int s0 = binStart[k];
    const unsigned int s1 = binStart[k + 1];
    const int tid = threadIdx.x;
    if (tid < 64) h[tid] = 0;
    __syncthreads();

    int4 rc[KMAX];
    unsigned int rs[KMAX];                  // (rank<<6)|sub
#pragma unroll
    for (int j = 0; j < KMAX; ++j) {
        const unsigned int idx = s0 + (unsigned)tid + (unsigned)j * 512u;
        rs[j] = 0xFFFFFFFFu;
        if (idx < s1) {
            rc[j] = recs[idx];
            const int c0 = cell512(__int_as_float(rc[j].x)) >> 4;
            const int c1 = cell512(__int_as_float(rc[j].y)) >> 4;
            const int c2 = cell512(__int_as_float(rc[j].z)) >> 4;
            const unsigned int sub = mortonN(c0, c1, c2, 5) & 63u;
            const unsigned int rank = atomicAdd(&h[sub], 1u);
            rs[j] = (rank << 6) | sub;
        }
    }
    __syncthreads();

    if (tid < 64) {
        const unsigned int v = h[tid];
        unsigned int run = v;
#pragma unroll
        for (int d = 1; d < 64; d <<= 1) {
            const unsigned int u = __shfl_up(run, (unsigned)d, 64);
            if (tid >= d) run += u;
        }
        pre[tid] = run - v;
    }
    __syncthreads();

#pragma unroll
    for (int j = 0; j < KMAX; ++j) {
        if (rs[j] != 0xFFFFFFFFu) {
            const unsigned int sub  = rs[j] & 63u;
            const unsigned int rank = rs[j] >> 6;
            recs[s0 + pre[sub] + rank] = rc[j];
        }
    }
}

// ---------------------------------------------------------------------------
// Sampler, forced-MLP, 1 point per thread (2 lanes/pt, 8 channels per lane):
// 12 inline-asm global_load_dwordx4 issued back-to-back, consumed per-plane
// behind counted s_waitcnt vmcnt(8/4/0) + sched_barrier (guide rule #18).
// Halved per-thread register footprint vs round 12 -> ~2x waves resident,
// same total lines-in-flight per CU but much better VALU/load overlap.
// ---------------------------------------------------------------------------
__global__ __launch_bounds__(256) void sample_sorted(
    const int4* __restrict__ recs, const __half* __restrict__ t,
    float* __restrict__ out, int B, int q, int r)
{
    const uint32_t bid  = blockIdx.x;
    const uint32_t xcd  = bid & 7u;
    const uint32_t slot = bid >> 3;
    const uint32_t base = (xcd < (uint32_t)r) ? xcd * (q + 1)
                                              : (uint32_t)r * (q + 1) + (xcd - r) * q;
    const uint32_t lb   = base + slot;

    const int tid = (int)(lb * 256u + threadIdx.x);
    const int p   = tid >> 1;
    const int h   = tid & 1;
    if (p >= B) return;

    const v4i rec = __builtin_nontemporal_load((const v4i*)&recs[p]);
    const float xv0 = __int_as_float(rec.x);
    const float xv1 = __int_as_float(rec.y);
    const float xv2 = __int_as_float(rec.z);

    // ---- coordinate math: weights + 12 byte offsets (32-bit) ----
    float w[3][4];
    uint32_t off[3][4];
    const uint32_t hofs = (uint32_t)h * 16u;
#pragma unroll
    for (int pl = 0; pl < 3; ++pl) {
        const float gx = (pl == 2) ? xv1 : xv0;
        const float gy = (pl == 0) ? xv1 : xv2;
        const float px = (gx + 1.0f) * 0.5f * (float)(R - 1);
        const float py = (gy + 1.0f) * 0.5f * (float)(R - 1);
        const float x0f = floorf(px), y0f = floorf(py);
        const float wx = px - x0f,   wy = py - y0f;
        int x0 = (int)x0f; x0 = min(max(x0, 0), R - 1);
        int y0 = (int)y0f; y0 = min(max(y0, 0), R - 1);
        const int x1 = min(x0 + 1, R - 1);
        const int y1 = min(y0 + 1, R - 1);
        off[pl][0] = ((uint32_t)(y0 * R) + (uint32_t)x0) * 32u + hofs;
        off[pl][1] = ((uint32_t)(y0 * R) + (uint32_t)x1) * 32u + hofs;
        off[pl][2] = ((uint32_t)(y1 * R) + (uint32_t)x0) * 32u + hofs;
        off[pl][3] = ((uint32_t)(y1 * R) + (uint32_t)x1) * 32u + hofs;
        w[pl][0] = (1.f - wx) * (1.f - wy);
        w[pl][1] = wx * (1.f - wy);
        w[pl][2] = (1.f - wx) * wy;
        w[pl][3] = wx * wy;
    }

    // ---- issue ALL 12 loads (volatile asm: order pinned, cannot sink) ----
    v4i raw[3][4];
#pragma unroll
    for (int pl = 0; pl < 3; ++pl) {
        const void* pb = (const char*)t + (size_t)pl * ((size_t)HW * C * 2);
#pragma unroll
        for (int c2 = 0; c2 < 4; ++c2)
            raw[pl][c2] = gload16(pb, off[pl][c2]);
    }

    float acc[8] = {1.f, 1.f, 1.f, 1.f, 1.f, 1.f, 1.f, 1.f};

    // ---- consume plane-by-plane behind counted waits ----
#pragma unroll
    for (int pl = 0; pl < 3; ++pl) {
        if (pl == 0) VMWAIT(8);
        else if (pl == 1) VMWAIT(4);
        else VMWAIT(0);
        const __half2* f0 = (const __half2*)&raw[pl][0];
        const __half2* f1 = (const __half2*)&raw[pl][1];
        const __half2* f2 = (const __half2*)&raw[pl][2];
        const __half2* f3 = (const __half2*)&raw[pl][3];
        const float w00 = w[pl][0], w01 = w[pl][1];
        const float w10 = w[pl][2], w11 = w[pl][3];
#pragma unroll
        for (int i2 = 0; i2 < 4; ++i2) {
            const float2 a0 = __half22float2(f0[i2]);
            const float2 a1 = __half22float2(f1[i2]);
            const float2 a2 = __half22float2(f2[i2]);
            const float2 a3 = __half22float2(f3[i2]);
            acc[2 * i2 + 0] *= a0.x * w00 + a1.x * w01 + a2.x * w10 + a3.x * w11;
            acc[2 * i2 + 1] *= a0.y * w00 + a1.y * w01 + a2.y * w10 + a3.y * w11;
        }
    }

    float* o = out + (size_t)rec.w * C + h * 8;
    const v4f o0 = { acc[0], acc[1], acc[2], acc[3] };
    const v4f o1 = { acc[4], acc[5], acc[6], acc[7] };
    __builtin_nontemporal_store(o0, (v4f*)(o + 0));
    __builtin_nontemporal_store(o1, (v4f*)(o + 4));
}

// ============================ fallback paths ================================
__global__ __launch_bounds__(256) void transpose_chw_hwc(
    const float* __restrict__ p0, const float* __restrict__ p1,
    const float* __restrict__ p2, float* __restrict__ dst)
{
    __shared__ float lds[64 * 17];
    const int y  = blockIdx.x;
    const int x0 = blockIdx.y * 64;
    const int pl = blockIdx.z;
    const float* src = (pl == 0) ? p0 : ((pl == 1) ? p1 : p2);
    const int tid = threadIdx.x;
    const int xl  = tid & 63;
    const int c0  = tid >> 6;
#pragma unroll
    for (int i = 0; i < 4; ++i) {
        const int c = c0 * 4 + i;
        lds[xl * 17 + c] = src[c * HW + y * R + x0 + xl];
    }
    __syncthreads();
    float* dbase = dst + ((size_t)pl * HW + (size_t)(y * R + x0)) * C;
#pragma unroll
    for (int i = 0; i < 4; ++i) {
        const int j = tid + i * 256;
        dbase[j] = lds[(j >> 4) * 17 + (j & 15)];
    }
}

__global__ __launch_bounds__(256) void sample_hwc(
    const float* __restrict__ x, const float* __restrict__ t,
    float* __restrict__ out, int B)
{
    const int tid = blockIdx.x * 256 + threadIdx.x;
    const int p   = tid >> 2;
    const int cg  = tid & 3;
    if (p >= B) return;

    const float xv0 = x[(size_t)p * 3 + 0];
    const float xv1 = x[(size_t)p * 3 + 1];
    const float xv2 = x[(size_t)p * 3 + 2];
    const float gxs[3] = { xv0, xv0, xv1 };
    const float gys[3] = { xv1, xv2, xv2 };
    float4 acc = make_float4(1.f, 1.f, 1.f, 1.f);

#pragma unroll
    for (int pl = 0; pl < 3; ++pl) {
        const float gx = gxs[pl], gy = gys[pl];
        const float px = (gx + 1.0f) * 0.5f * (float)(R - 1);
        const float py = (gy + 1.0f) * 0.5f * (float)(R - 1);
        const float x0f = floorf(px), y0f = floorf(py);
        const float wx = px - x0f,   wy = py - y0f;
        int x0 = (int)x0f; x0 = min(max(x0, 0), R - 1);
        int y0 = (int)y0f; y0 = min(max(y0, 0), R - 1);
        const int x1 = min(x0 + 1, R - 1);
        const int y1 = min(y0 + 1, R - 1);

        const float* pb = t + (size_t)pl * (size_t)(HW * C) + cg * 4;
        const float4 p00 = *(const float4*)(pb + (size_t)(y0 * R + x0) * C);
        const float4 p01 = *(const float4*)(pb + (size_t)(y0 * R + x1) * C);
        const float4 p10 = *(const float4*)(pb + (size_t)(y1 * R + x0) * C);
        const float4 p11 = *(const float4*)(pb + (size_t)(y1 * R + x1) * C);

        const float w00 = (1.f - wx) * (1.f - wy);
        const float w01 = wx * (1.f - wy);
        const float w10 = (1.f - wx) * wy;
        const float w11 = wx * wy;

        float4 fv;
        fv.x = p00.x * w00 + p01.x * w01 + p10.x * w10 + p11.x * w11;
        fv.y = p00.y * w00 + p01.y * w01 + p10.y * w10 + p11.y * w11;
        fv.z = p00.z * w00 + p01.z * w01 + p10.z * w10 + p11.z * w11;
        fv.w = p00.w * w00 + p01.w * w01 + p10.w * w10 + p11.w * w11;

        acc.x *= fv.x; acc.y *= fv.y; acc.z *= fv.z; acc.w *= fv.w;
    }

    *(float4*)(out + (size_t)p * C + cg * 4) = acc;
}

__global__ __launch_bounds__(256) void sample_chw(
    const float* __restrict__ x,
    const float* __restrict__ p0, const float* __restrict__ p1,
    const float* __restrict__ p2, float* __restrict__ out, int B)
{
    const int tid = blockIdx.x * 256 + threadIdx.x;
    const int p   = tid >> 2;
    const int cg  = tid & 3;
    if (p >= B) return;
    const float xv0 = x[(size_t)p * 3 + 0];
    const float xv1 = x[(size_t)p * 3 + 1];
    const float xv2 = x[(size_t)p * 3 + 2];
    const float gxs[3] = { xv0, xv0, xv1 };
    const float gys[3] = { xv1, xv2, xv2 };
    const float* planes[3] = { p0, p1, p2 };
    float acc[4] = {1.f, 1.f, 1.f, 1.f};
#pragma unroll
    for (int pl = 0; pl < 3; ++pl) {
        const float gx = gxs[pl], gy = gys[pl];
        const float px = (gx + 1.0f) * 0.5f * (float)(R - 1);
        const float py = (gy + 1.0f) * 0.5f * (float)(R - 1);
        const float x0f = floorf(px), y0f = floorf(py);
        const float wx = px - x0f,   wy = py - y0f;
        int x0 = (int)x0f; x0 = min(max(x0, 0), R - 1);
        int y0 = (int)y0f; y0 = min(max(y0, 0), R - 1);
        const int x1 = min(x0 + 1, R - 1);
        const int y1 = min(y0 + 1, R - 1);
        const float w00 = (1.f - wx) * (1.f - wy);
        const float w01 = wx * (1.f - wy);
        const float w10 = (1.f - wx) * wy;
        const float w11 = wx * wy;
        const float* pb = planes[pl];
#pragma unroll
        for (int k = 0; k < 4; ++k) {
            const int c = cg * 4 + k;
            const float* b2 = pb + (size_t)c * HW;
            const float v00 = b2[y0 * R + x0];
            const float v01 = b2[y0 * R + x1];
            const float v10 = b2[y1 * R + x0];
            const float v11 = b2[y1 * R + x1];
            acc[k] *= v00 * w00 + v01 * w01 + v10 * w10 + v11 * w11;
        }
    }
    float* o = out + (size_t)p * C + cg * 4;
    o[0] = acc[0]; o[1] = acc[1]; o[2] = acc[2]; o[3] = acc[3];
}

// ===========================================================================
extern "C" void kernel_launch(void* const* d_in, const int* in_sizes, int n_in,
                              void* d_out, int out_size, void* d_ws, size_t ws_size,
                              hipStream_t stream) {
    const float* x  = (const float*)d_in[0];
    const float* p0 = (const float*)d_in[1];
    const float* p1 = (const float*)d_in[2];
    const float* p2 = (const float*)d_in[3];
    float* out = (float*)d_out;
    const int B = in_sizes[0] / 3;

    const size_t t_bytes    = (size_t)3 * HW * C * sizeof(__half);     // 24 MiB
    const size_t recs_bytes = (size_t)B * 16;                          // 32 MB
    const size_t cnt_bytes  = (size_t)NCNT * 4;                        // 16 KiB
    const size_t bs_bytes   = (size_t)(NB9 + 1) * 4;

    const size_t off_t      = 0;
    const size_t off_recs   = (t_bytes + 255) & ~(size_t)255;
    const size_t off_counts = (off_recs + recs_bytes + 255) & ~(size_t)255;
    const size_t off_cursor = (off_counts + cnt_bytes + 255) & ~(size_t)255;
    const size_t off_bs     = (off_cursor + cnt_bytes + 255) & ~(size_t)255;
    const size_t need_full  = off_bs + bs_bytes;

    const size_t need_fp32  = (size_t)3 * HW * C * sizeof(float);      // 48 MiB

    if (d_ws != nullptr && ws_size >= need_full) {
        __half*       t      = (__half*)((char*)d_ws + off_t);
        int4*         recs   = (int4*)((char*)d_ws + off_recs);
        unsigned int* counts = (unsigned int*)((char*)d_ws + off_counts);
        unsigned int* cursor = (unsigned int*)((char*)d_ws + off_cursor);
        unsigned int* bstart = (unsigned int*)((char*)d_ws + off_bs);

        dim3 tg(R, R / 64, 3);
        transpose_chw_hwc_h<<<tg, 256, 0, stream>>>(p0, p1, p2, t);

        hipMemsetAsync(counts, 0, cnt_bytes, stream);
        const int nblkP = (B + CHUNK - 1) / CHUNK;
        hist_pts<<<nblkP, 256, 0, stream>>>(x, counts, B);
        scan_counts<<<1, 1024, 0, stream>>>(counts, cursor, bstart);
        scatter_pts<<<nblkP, 256, 0, stream>>>(x, cursor, recs, B);
        refine_pts<<<NB9, 512, 0, stream>>>(bstart, recs);

        const int nthr2 = 2 * B;                   // 2 lanes/pt, 1 pt/thread
        const int nblk2 = (nthr2 + 255) / 256;
        const int q = nblk2 / 8, r = nblk2 % 8;
        sample_sorted<<<nblk2, 256, 0, stream>>>(recs, t, out, B, q, r);
    } else if (d_ws != nullptr && ws_size >= need_fp32) {
        float* tf = (float*)d_ws;
        dim3 tg(R, R / 64, 3);
        transpose_chw_hwc<<<tg, 256, 0, stream>>>(p0, p1, p2, tf);
        const int nthr = B * 4;
        const int nblk = (nthr + 255) / 256;
        sample_hwc<<<nblk, 256, 0, stream>>>(x, tf, out, B);
    } else {
        const int nthr = B * 4;
        const int nblk = (nthr + 255) / 256;
        sample_chw<<<nblk, 256, 0, stream>>>(x, p0, p1, p2, out, B);
    }
}